// Round 4
// baseline (726.875 us; speedup 1.0000x reference)
//
#include <hip/hip_runtime.h>

#define N_NODES 100000
#define N_EDGES 1600000
#define NB      1024
#define EPSF    1e-5f
#define GRP_SH  2
#define GRP_N   4
#define NGRP    25000            // N_NODES / GRP_N exact
#define SCH     128
#define SNB     ((NGRP + SCH - 1) / SCH)   // 196

__device__ __forceinline__ float bf2f(unsigned short u) {
    union { unsigned int i; float f; } v; v.i = ((unsigned int)u) << 16; return v.f;
}
__device__ __forceinline__ unsigned short f2bf(float f) {
    union { float ff; unsigned int i; } v; v.ff = f;
    unsigned int r = v.i + 0x7FFFu + ((v.i >> 16) & 1u);   // RNE
    return (unsigned short)(r >> 16);
}

// -------------- per-channel mean/var(ddof=1) -> scale/shift --------------
template<int C>
__global__ __launch_bounds__(256) void stats_kernel(const float* __restrict__ jet,
                                                    const float* __restrict__ g,
                                                    const float* __restrict__ b,
                                                    float* __restrict__ scale,
                                                    float* __restrict__ shift) {
    int c = blockIdx.x;
    int t = threadIdx.x;
    float s = 0.f, s2 = 0.f;
    for (int r = t; r < NB; r += 256) {
        float v = jet[r * C + c];
        s += v; s2 += v * v;
    }
    __shared__ float ls[256], ls2[256];
    ls[t] = s; ls2[t] = s2;
    __syncthreads();
    for (int ofs = 128; ofs > 0; ofs >>= 1) {
        if (t < ofs) { ls[t] += ls[t + ofs]; ls2[t] += ls2[t + ofs]; }
        __syncthreads();
    }
    if (t == 0) {
        float mean = ls[0] / (float)NB;
        float var  = (ls2[0] - (float)NB * mean * mean) / (float)(NB - 1);
        float sc   = g[c] / sqrtf(var + EPSF);
        scale[c] = sc;
        shift[c] = b[c] - mean * sc;
    }
}

// ---------------- count kernels ------------------------------------------
__global__ __launch_bounds__(256) void countG_kernel(const int* __restrict__ head,
                                                     int* __restrict__ gcnt) {
    int e = blockIdx.x * 256 + threadIdx.x;
    if (e < N_EDGES) atomicAdd(&gcnt[head[e] >> GRP_SH], 1);
}
__global__ __launch_bounds__(256) void countI_kernel(const int* __restrict__ ind,
                                                     int* __restrict__ cntI) {
    int n = blockIdx.x * 256 + threadIdx.x;
    if (n < N_NODES) atomicAdd(&cntI[ind[n]], 1);
}

// ---------------- scans ---------------------------------------------------
__global__ __launch_bounds__(SCH) void scanA_kernel(const int* __restrict__ cnt,
                                                    int* __restrict__ part, int n) {
    __shared__ int ls[SCH];
    int t = threadIdx.x;
    int i = blockIdx.x * SCH + t;
    ls[t] = (i < n) ? cnt[i] : 0;
    __syncthreads();
    for (int ofs = SCH / 2; ofs > 0; ofs >>= 1) {
        if (t < ofs) ls[t] += ls[t + ofs];
        __syncthreads();
    }
    if (t == 0) part[blockIdx.x] = ls[0];
}

// single-block scan (n <= 1024); EXCLUSIVE prefix to out (and out2)
__global__ __launch_bounds__(1024) void scanB_kernel(const int* __restrict__ in,
                                                     int* __restrict__ out,
                                                     int* __restrict__ out2, int n) {
    __shared__ int ls[1024];
    int t = threadIdx.x;
    int v = (t < n) ? in[t] : 0;
    ls[t] = v;
    __syncthreads();
    for (int ofs = 1; ofs < 1024; ofs <<= 1) {
        int u = (t >= ofs) ? ls[t - ofs] : 0;
        __syncthreads();
        ls[t] += u;
        __syncthreads();
    }
    if (t < n) {
        int e = ls[t] - v;
        out[t] = e;
        if (out2) out2[t] = e;
    }
}

__global__ __launch_bounds__(SCH) void scanC_kernel(const int* __restrict__ cnt,
                                                    const int* __restrict__ poff,
                                                    int* __restrict__ base,
                                                    int* __restrict__ cursor, int n) {
    __shared__ int ls[SCH];
    int t = threadIdx.x;
    int i = blockIdx.x * SCH + t;
    int v = (i < n) ? cnt[i] : 0;
    ls[t] = v;
    __syncthreads();
    for (int ofs = 1; ofs < SCH; ofs <<= 1) {
        int u = (t >= ofs) ? ls[t - ofs] : 0;
        __syncthreads();
        ls[t] += u;
        __syncthreads();
    }
    if (i < n) {
        int bse = poff[blockIdx.x] + ls[t] - v;
        base[i] = bse;
        cursor[i] = bse;
    }
}

// ---------------- scatters ------------------------------------------------
__global__ __launch_bounds__(256) void escatterG_kernel(const int* __restrict__ head,
                                                        const int* __restrict__ tail,
                                                        const float* __restrict__ pf,
                                                        int* __restrict__ gcur,
                                                        unsigned* __restrict__ tailp,
                                                        float* __restrict__ pf_s) {
    int e = blockIdx.x * 256 + threadIdx.x;
    if (e >= N_EDGES) return;
    int h = head[e];
    int slot = atomicAdd(&gcur[h >> GRP_SH], 1);
    tailp[slot] = (unsigned)tail[e] | ((unsigned)(h & (GRP_N - 1)) << 20);
    ((float4*)pf_s)[slot] = ((const float4*)pf)[e];
}

__global__ __launch_bounds__(256) void scatterI_kernel(const int* __restrict__ ind,
                                                       int* __restrict__ cursorI,
                                                       int* __restrict__ order) {
    int n = blockIdx.x * 256 + threadIdx.x;
    if (n < N_NODES) {
        int pos = atomicAdd(&cursorI[ind[n]], 1);
        order[pos] = n;
    }
}

// ---------- bucket jet: jet[b,c] = sum_{n in bucket b} x[n,c]*w[n] -------
template<int C>
__global__ __launch_bounds__(256) void bucket_jet_kernel(const float* __restrict__ xx,
                                                         const float* __restrict__ w,
                                                         const int* __restrict__ order,
                                                         const int* __restrict__ baseI,
                                                         const int* __restrict__ cntI,
                                                         float* __restrict__ jet) {
    constexpr int G = 256 / C;
    __shared__ float red[256];
    int b = blockIdx.x;
    int g = threadIdx.x / C;
    int c = threadIdx.x % C;
    int s0 = baseI[b], m = cntI[b];
    float s = 0.f;
    for (int k = g; k < m; k += G) {
        int n = order[s0 + k];
        s += xx[n * C + c] * w[n];
    }
    red[threadIdx.x] = s;
    __syncthreads();
    for (int half = G / 2; half > 0; half >>= 1) {
        if (g < half) red[g * C + c] += red[(g + half) * C + c];
        __syncthreads();
    }
    if (g == 0) jet[b * C + c] = red[c];
}

// --------- fused1: shortcut GEMM + bn1+relu + @W1^T * w  -----------------
#define TILE1 32
__global__ __launch_bounds__(256) void fused1_kernel(const float* __restrict__ x,
                                                     const float* __restrict__ w,
                                                     const float* __restrict__ scale,
                                                     const float* __restrict__ shift,
                                                     const float* __restrict__ Wsc,
                                                     const float* __restrict__ W1,
                                                     unsigned short* __restrict__ hs,
                                                     float* __restrict__ out) {
    __shared__ __align__(16) float xs[TILE1][68];
    __shared__ __align__(16) float xn[TILE1][68];
    __shared__ __align__(16) float Wl[160][68];
    int tid = threadIdx.x;
    int n0  = blockIdx.x * TILE1;

    for (int i = tid; i < 128 * 64; i += 256) Wl[i >> 6][i & 63] = Wsc[i];
    for (int i = tid; i < 32 * 64;  i += 256) Wl[128 + (i >> 6)][i & 63] = W1[i];
    for (int i = tid; i < TILE1 * 64; i += 256) {
        int r = i >> 6, c = i & 63;
        int n = n0 + r;
        float v = (n < N_NODES) ? x[n * 64 + c] : 0.f;
        xs[r][c] = v;
        float vn = v * scale[c] + shift[c];
        xn[r][c] = vn > 0.f ? vn : 0.f;
    }
    __syncthreads();

    int r0 = tid >> 4;     // 0..15 -> rows r0, r0+16
    int s  = tid & 15;     // 0..15
    float acc[2][10];
#pragma unroll
    for (int q = 0; q < 2; q++)
#pragma unroll
        for (int k = 0; k < 10; k++) acc[q][k] = 0.f;

    for (int c = 0; c < 64; c += 4) {
        float4 xr0 = *(const float4*)&xs[r0][c];
        float4 xr1 = *(const float4*)&xs[r0 + 16][c];
        float4 xn0 = *(const float4*)&xn[r0][c];
        float4 xn1 = *(const float4*)&xn[r0 + 16][c];
#pragma unroll
        for (int k = 0; k < 10; k++) {
            int row = (k < 8) ? (s + 16 * k) : (128 + s + 16 * (k - 8));
            float4 wv = *(const float4*)&Wl[row][c];
            float4 a0 = (k < 8) ? xr0 : xn0;
            float4 a1 = (k < 8) ? xr1 : xn1;
            acc[0][k] += a0.x * wv.x + a0.y * wv.y + a0.z * wv.z + a0.w * wv.w;
            acc[1][k] += a1.x * wv.x + a1.y * wv.y + a1.z * wv.z + a1.w * wv.w;
        }
    }
#pragma unroll
    for (int q = 0; q < 2; q++) {
        int n = n0 + r0 + 16 * q;
        if (n < N_NODES) {
            float ww = w[n];
#pragma unroll
            for (int k = 0; k < 8; k++) out[(size_t)n * 128 + s + 16 * k] = acc[q][k];
            hs[n * 32 + s]      = f2bf(acc[q][8] * ww);
            hs[n * 32 + s + 16] = f2bf(acc[q][9] * ww);
        }
    }
}

// ---------- gatherS: wave-per-node scan over its 4-node group ------------
__global__ __launch_bounds__(256) void gatherS_kernel(const int* __restrict__ gbase,
                                                      const int* __restrict__ gcnt,
                                                      const unsigned* __restrict__ tailp,
                                                      const float* __restrict__ pf_s,
                                                      const unsigned short* __restrict__ hs,
                                                      float* __restrict__ agg) {
    int g = blockIdx.x;
    int wv = threadIdx.x >> 6;
    int lane = threadIdx.x & 63;
    int n = (g << GRP_SH) + wv;
    int i = lane >> 1;            // h channel 0..31
    int th = (lane & 1) << 1;     // pf offset 0 or 2
    int s0 = gbase[g], c = gcnt[g];
    unsigned my = (unsigned)wv;
    float a0 = 0.f, a1 = 0.f;
    int k = 0;
    for (; k + 2 <= c; k += 2) {
        unsigned p0 = tailp[s0 + k], p1 = tailp[s0 + k + 1];
        float2 q0 = *(const float2*)&pf_s[(size_t)(s0 + k) * 4 + th];
        float2 q1 = *(const float2*)&pf_s[(size_t)(s0 + k + 1) * 4 + th];
        if ((p0 >> 20) == my) {
            float h = bf2f(hs[(p0 & 0xFFFFFu) * 32 + i]);
            a0 += h * q0.x; a1 += h * q0.y;
        }
        if ((p1 >> 20) == my) {
            float h = bf2f(hs[(p1 & 0xFFFFFu) * 32 + i]);
            a0 += h * q1.x; a1 += h * q1.y;
        }
    }
    if (k < c) {
        unsigned p0 = tailp[s0 + k];
        float2 q0 = *(const float2*)&pf_s[(size_t)(s0 + k) * 4 + th];
        if ((p0 >> 20) == my) {
            float h = bf2f(hs[(p0 & 0xFFFFFu) * 32 + i]);
            a0 += h * q0.x; a1 += h * q0.y;
        }
    }
    *(float2*)&agg[(size_t)n * 128 + lane * 2] = make_float2(a0, a1);
}

// -------- legacy atomic edge scatter (ultimate fallback) -----------------
__global__ __launch_bounds__(256) void edge_kernel(const int* __restrict__ head,
                                                   const int* __restrict__ tail,
                                                   const float* __restrict__ pf,
                                                   const unsigned short* __restrict__ hs,
                                                   float* __restrict__ agg) {
    long long tid = (long long)blockIdx.x * 256 + threadIdx.x;
    if (tid >= (long long)N_EDGES * 128) return;
    int e = (int)(tid >> 7);
    int j = (int)(tid & 127);
    int i = j >> 2, t = j & 3;
    float v = bf2f(hs[tail[e] * 32 + i]) * pf[e * 4 + t];
    atomicAdd(&agg[head[e] * 128 + j], v);
}

// ------- fused2: y = relu(bn(x)) @ W^T (+resid), 64-row tile, 4x4 reg ----
#define TILE2 64
__global__ __launch_bounds__(256) void fused2_kernel(const float* __restrict__ xin,
                                                     const float* __restrict__ scale,
                                                     const float* __restrict__ shift,
                                                     const float* __restrict__ W,
                                                     float* __restrict__ yout,
                                                     const float* __restrict__ resid) {
    __shared__ __align__(16) float xn[TILE2][128];   // swizzled c ^= (r&3)<<2
    __shared__ __align__(16) float Wl[64][128];      // swizzled c ^= (r&7)<<2
    int tid = threadIdx.x;
    int n0  = blockIdx.x * TILE2;

    for (int idx = tid; idx < TILE2 * 32; idx += 256) {
        int r = idx >> 5, c = (idx & 31) << 2;
        int n = n0 + r;
        float4 v = make_float4(0.f, 0.f, 0.f, 0.f);
        if (n < N_NODES) v = *(const float4*)&xin[(size_t)n * 128 + c];
        float4 sc = *(const float4*)&scale[c];
        float4 sh = *(const float4*)&shift[c];
        float4 o;
        o.x = fmaxf(fmaf(v.x, sc.x, sh.x), 0.f);
        o.y = fmaxf(fmaf(v.y, sc.y, sh.y), 0.f);
        o.z = fmaxf(fmaf(v.z, sc.z, sh.z), 0.f);
        o.w = fmaxf(fmaf(v.w, sc.w, sh.w), 0.f);
        *(float4*)&xn[r][c ^ ((r & 3) << 2)] = o;
    }
    for (int idx = tid; idx < 64 * 32; idx += 256) {
        int r = idx >> 5, c = (idx & 31) << 2;
        *(float4*)&Wl[r][c ^ ((r & 7) << 2)] = *(const float4*)&W[r * 128 + c];
    }
    __syncthreads();

    int r0 = tid >> 4;   // 0..15, rows r0+16q
    int s  = tid & 15;   // 0..15, cols s+16k (phase A), +64 (phase B)
    float accA[4][4], accB[4][4];
#pragma unroll
    for (int q = 0; q < 4; q++)
#pragma unroll
        for (int k = 0; k < 4; k++) accA[q][k] = 0.f;

    for (int c = 0; c < 128; c += 4) {
        float4 xv[4];
#pragma unroll
        for (int q = 0; q < 4; q++) {
            int r = r0 + (q << 4);
            xv[q] = *(const float4*)&xn[r][c ^ ((r & 3) << 2)];
        }
#pragma unroll
        for (int k = 0; k < 4; k++) {
            int row = s + (k << 4);
            float4 wv = *(const float4*)&Wl[row][c ^ ((row & 7) << 2)];
#pragma unroll
            for (int q = 0; q < 4; q++)
                accA[q][k] += xv[q].x * wv.x + xv[q].y * wv.y + xv[q].z * wv.z + xv[q].w * wv.w;
        }
    }
    __syncthreads();
    for (int idx = tid; idx < 64 * 32; idx += 256) {
        int r = idx >> 5, c = (idx & 31) << 2;
        *(float4*)&Wl[r][c ^ ((r & 7) << 2)] = *(const float4*)&W[(64 + r) * 128 + c];
    }
    __syncthreads();
#pragma unroll
    for (int q = 0; q < 4; q++)
#pragma unroll
        for (int k = 0; k < 4; k++) accB[q][k] = 0.f;

    for (int c = 0; c < 128; c += 4) {
        float4 xv[4];
#pragma unroll
        for (int q = 0; q < 4; q++) {
            int r = r0 + (q << 4);
            xv[q] = *(const float4*)&xn[r][c ^ ((r & 3) << 2)];
        }
#pragma unroll
        for (int k = 0; k < 4; k++) {
            int row = s + (k << 4);
            float4 wv = *(const float4*)&Wl[row][c ^ ((row & 7) << 2)];
#pragma unroll
            for (int q = 0; q < 4; q++)
                accB[q][k] += xv[q].x * wv.x + xv[q].y * wv.y + xv[q].z * wv.z + xv[q].w * wv.w;
        }
    }
#pragma unroll
    for (int q = 0; q < 4; q++) {
        int n = n0 + r0 + (q << 4);
        if (n < N_NODES) {
#pragma unroll
            for (int k = 0; k < 4; k++) {
                int oA = s + (k << 4), oB = 64 + oA;
                float vA = accA[q][k], vB = accB[q][k];
                if (resid) {
                    vA += resid[(size_t)n * 128 + oA];
                    vB += resid[(size_t)n * 128 + oB];
                }
                yout[(size_t)n * 128 + oA] = vA;
                yout[(size_t)n * 128 + oB] = vB;
            }
        }
    }
}

extern "C" void kernel_launch(void* const* d_in, const int* in_sizes, int n_in,
                              void* d_out, int out_size, void* d_ws, size_t ws_size,
                              hipStream_t stream) {
    const float* x    = (const float*)d_in[0];
    const float* w    = (const float*)d_in[1];
    const float* pf   = (const float*)d_in[2];
    const int*   head = (const int*)d_in[3];
    const int*   tail = (const int*)d_in[4];
    const int*   ind  = (const int*)d_in[5];
    const float* Wsc  = (const float*)d_in[6];
    const float* g1   = (const float*)d_in[7];
    const float* b1   = (const float*)d_in[8];
    const float* W1   = (const float*)d_in[9];
    const float* g2   = (const float*)d_in[10];
    const float* b2   = (const float*)d_in[11];
    const float* W2   = (const float*)d_in[12];
    const float* g3   = (const float*)d_in[13];
    const float* b3   = (const float*)d_in[14];
    const float* W3   = (const float*)d_in[15];
    float* out = (float*)d_out;

    char* p = (char*)d_ws;
    unsigned short* hs = (unsigned short*)p;  p += (size_t)N_NODES * 32 * 2;   // 6.4MB
    float* agg  = (float*)p;                  p += (size_t)N_NODES * 128 * 4;  // 51.2MB
    float* jet1 = (float*)p;                  p += 1024 * 64 * 4;
    float* jet2 = (float*)p;                  p += 1024 * 128 * 4;
    float* jet3 = (float*)p;                  p += 1024 * 128 * 4;
    float* sc1 = (float*)p; p += 64 * 4;  float* sh1 = (float*)p; p += 64 * 4;
    float* sc2 = (float*)p; p += 128 * 4; float* sh2 = (float*)p; p += 128 * 4;
    float* sc3 = (float*)p; p += 128 * 4; float* sh3 = (float*)p; p += 128 * 4;
    int* gcnt  = (int*)p; p += NGRP * 4;
    int* gbase = (int*)p; p += NGRP * 4;
    int* gcur  = (int*)p; p += NGRP * 4;
    int* part  = (int*)p; p += 1024 * 4;
    int* cntI  = (int*)p; p += 1024 * 4;
    int* baseI = (int*)p; p += 1024 * 4;
    int* cursorI = (int*)p; p += 1024 * 4;
    int* order = (int*)p; p += (size_t)N_NODES * 4;
    unsigned* tailp = (unsigned*)p; p += (size_t)N_EDGES * 4;
    float* pf_s = (float*)p; p += (size_t)N_EDGES * 16;
    size_t need = (size_t)(p - (char*)d_ws);
    bool fast = ws_size >= need;

    // ---- indicator-CSR (atomic-free jets) ----
    hipMemsetAsync(cntI, 0, 1024 * sizeof(int), stream);
    countI_kernel<<<(N_NODES + 255) / 256, 256, 0, stream>>>(ind, cntI);
    scanB_kernel<<<1, 1024, 0, stream>>>(cntI, baseI, cursorI, 1024);
    scatterI_kernel<<<(N_NODES + 255) / 256, 256, 0, stream>>>(ind, cursorI, order);

    // ---- BN1 stats ----
    bucket_jet_kernel<64><<<1024, 256, 0, stream>>>(x, w, order, baseI, cntI, jet1);
    stats_kernel<64><<<64, 256, 0, stream>>>(jet1, g1, b1, sc1, sh1);

    // ---- shortcut + layer1 ----
    fused1_kernel<<<(N_NODES + TILE1 - 1) / TILE1, 256, 0, stream>>>(
        x, w, sc1, sh1, Wsc, W1, hs, out);

    // ---- edge message passing ----
    if (fast) {
        hipMemsetAsync(gcnt, 0, NGRP * sizeof(int), stream);
        countG_kernel<<<(N_EDGES + 255) / 256, 256, 0, stream>>>(head, gcnt);
        scanA_kernel<<<SNB, SCH, 0, stream>>>(gcnt, part, NGRP);
        scanB_kernel<<<1, 1024, 0, stream>>>(part, part, nullptr, SNB);
        scanC_kernel<<<SNB, SCH, 0, stream>>>(gcnt, part, gbase, gcur, NGRP);
        escatterG_kernel<<<(N_EDGES + 255) / 256, 256, 0, stream>>>(
            head, tail, pf, gcur, tailp, pf_s);
        gatherS_kernel<<<NGRP, 256, 0, stream>>>(gbase, gcnt, tailp, pf_s, hs, agg);
    } else {
        hipMemsetAsync(agg, 0, (size_t)N_NODES * 128 * sizeof(float), stream);
        edge_kernel<<<(int)(((long long)N_EDGES * 128) / 256), 256, 0, stream>>>(
            head, tail, pf, hs, agg);
    }

    // ---- BN2 + layer2 (in place on agg) ----
    bucket_jet_kernel<128><<<1024, 256, 0, stream>>>(agg, w, order, baseI, cntI, jet2);
    stats_kernel<128><<<128, 256, 0, stream>>>(jet2, g2, b2, sc2, sh2);
    fused2_kernel<<<(N_NODES + TILE2 - 1) / TILE2, 256, 0, stream>>>(
        agg, sc2, sh2, W2, agg, nullptr);

    // ---- BN3 + layer3 + shortcut add ----
    bucket_jet_kernel<128><<<1024, 256, 0, stream>>>(agg, w, order, baseI, cntI, jet3);
    stats_kernel<128><<<128, 256, 0, stream>>>(jet3, g3, b3, sc3, sh3);
    fused2_kernel<<<(N_NODES + TILE2 - 1) / TILE2, 256, 0, stream>>>(
        agg, sc3, sh3, W3, out, out);

    (void)in_sizes; (void)n_in; (void)out_size;
}

// Round 5
// 712.062 us; speedup vs baseline: 1.0208x; 1.0208x over previous
//
#include <hip/hip_runtime.h>

#define N_NODES 100000
#define N_EDGES 1600000
#define NB      1024
#define EPSF    1e-5f

#define SCHUNK 128
#define SNBLK ((N_NODES + SCHUNK - 1) / SCHUNK)   // 782

__device__ __forceinline__ float bf2f(unsigned short u) {
    union { unsigned int i; float f; } v; v.i = ((unsigned int)u) << 16; return v.f;
}
__device__ __forceinline__ unsigned short f2bf(float f) {
    union { float ff; unsigned int i; } v; v.ff = f;
    unsigned int r = v.i + 0x7FFFu + ((v.i >> 16) & 1u);   // RNE
    return (unsigned short)(r >> 16);
}

// -------------- per-channel mean/var(ddof=1) -> scale/shift --------------
template<int C>
__global__ __launch_bounds__(256) void stats_kernel(const float* __restrict__ jet,
                                                    const float* __restrict__ g,
                                                    const float* __restrict__ b,
                                                    float* __restrict__ scale,
                                                    float* __restrict__ shift) {
    int c = blockIdx.x;
    int t = threadIdx.x;
    float s = 0.f, s2 = 0.f;
    for (int r = t; r < NB; r += 256) {
        float v = jet[r * C + c];
        s += v; s2 += v * v;
    }
    __shared__ float ls[256], ls2[256];
    ls[t] = s; ls2[t] = s2;
    __syncthreads();
    for (int ofs = 128; ofs > 0; ofs >>= 1) {
        if (t < ofs) { ls[t] += ls[t + ofs]; ls2[t] += ls2[t + ofs]; }
        __syncthreads();
    }
    if (t == 0) {
        float mean = ls[0] / (float)NB;
        float var  = (ls2[0] - (float)NB * mean * mean) / (float)(NB - 1);
        float sc   = g[c] / sqrtf(var + EPSF);
        scale[c] = sc;
        shift[c] = b[c] - mean * sc;
    }
}

// ---------------- count kernels ------------------------------------------
__global__ __launch_bounds__(256) void count_head_kernel(const int* __restrict__ head,
                                                         int* __restrict__ cnt) {
    int e = blockIdx.x * 256 + threadIdx.x;
    if (e < N_EDGES) atomicAdd(&cnt[head[e]], 1);
}
__global__ __launch_bounds__(256) void countI_kernel(const int* __restrict__ ind,
                                                     int* __restrict__ cntI) {
    int n = blockIdx.x * 256 + threadIdx.x;
    if (n < N_NODES) atomicAdd(&cntI[ind[n]], 1);
}

// ---------------- scans ---------------------------------------------------
__global__ __launch_bounds__(SCHUNK) void scanA_kernel(const int* __restrict__ cnt,
                                                       int* __restrict__ part, int n) {
    __shared__ int ls[SCHUNK];
    int t = threadIdx.x;
    int i = blockIdx.x * SCHUNK + t;
    ls[t] = (i < n) ? cnt[i] : 0;
    __syncthreads();
    for (int ofs = SCHUNK / 2; ofs > 0; ofs >>= 1) {
        if (t < ofs) ls[t] += ls[t + ofs];
        __syncthreads();
    }
    if (t == 0) part[blockIdx.x] = ls[0];
}

// single-block scan (n <= 1024); EXCLUSIVE prefix to out (and out2)
__global__ __launch_bounds__(1024) void scanB_kernel(const int* __restrict__ in,
                                                     int* __restrict__ out,
                                                     int* __restrict__ out2, int n) {
    __shared__ int ls[1024];
    int t = threadIdx.x;
    int v = (t < n) ? in[t] : 0;
    ls[t] = v;
    __syncthreads();
    for (int ofs = 1; ofs < 1024; ofs <<= 1) {
        int u = (t >= ofs) ? ls[t - ofs] : 0;
        __syncthreads();
        ls[t] += u;
        __syncthreads();
    }
    if (t < n) {
        int e = ls[t] - v;
        out[t] = e;
        if (out2) out2[t] = e;
    }
}

__global__ __launch_bounds__(SCHUNK) void scanC_kernel(const int* __restrict__ cnt,
                                                       const int* __restrict__ poff,
                                                       int* __restrict__ base,
                                                       int* __restrict__ cursor, int n) {
    __shared__ int ls[SCHUNK];
    int t = threadIdx.x;
    int i = blockIdx.x * SCHUNK + t;
    int v = (i < n) ? cnt[i] : 0;
    ls[t] = v;
    __syncthreads();
    for (int ofs = 1; ofs < SCHUNK; ofs <<= 1) {
        int u = (t >= ofs) ? ls[t - ofs] : 0;
        __syncthreads();
        ls[t] += u;
        __syncthreads();
    }
    if (i < n) {
        int bse = poff[blockIdx.x] + ls[t] - v;
        base[i] = bse;
        cursor[i] = bse;
    }
}

// ---------------- scatter: eid only (4B random writes) -------------------
__global__ __launch_bounds__(256) void escatterE_kernel(const int* __restrict__ head,
                                                        int* __restrict__ cursor,
                                                        int* __restrict__ eid) {
    int e = blockIdx.x * 256 + threadIdx.x;
    if (e >= N_EDGES) return;
    int slot = atomicAdd(&cursor[head[e]], 1);
    eid[slot] = e;
}

// ------- streaming permute: slot-ordered tail_s/pf_s, coalesced writes ---
__global__ __launch_bounds__(256) void permute_kernel(const int* __restrict__ eid,
                                                      const int* __restrict__ tail,
                                                      const float* __restrict__ pf,
                                                      int* __restrict__ tail_s,
                                                      float* __restrict__ pf_s) {
    int s = blockIdx.x * 256 + threadIdx.x;
    if (s >= N_EDGES) return;
    int e = eid[s];
    tail_s[s] = tail[e];
    ((float4*)pf_s)[s] = ((const float4*)pf)[e];
}

__global__ __launch_bounds__(256) void scatterI_kernel(const int* __restrict__ ind,
                                                       int* __restrict__ cursorI,
                                                       int* __restrict__ order) {
    int n = blockIdx.x * 256 + threadIdx.x;
    if (n < N_NODES) {
        int pos = atomicAdd(&cursorI[ind[n]], 1);
        order[pos] = n;
    }
}

// ---------- bucket jet: jet[b,c] = sum_{n in bucket b} x[n,c]*w[n] -------
template<int C>
__global__ __launch_bounds__(256) void bucket_jet_kernel(const float* __restrict__ xx,
                                                         const float* __restrict__ w,
                                                         const int* __restrict__ order,
                                                         const int* __restrict__ baseI,
                                                         const int* __restrict__ cntI,
                                                         float* __restrict__ jet) {
    constexpr int G = 256 / C;
    __shared__ float red[256];
    int b = blockIdx.x;
    int g = threadIdx.x / C;
    int c = threadIdx.x % C;
    int s0 = baseI[b], m = cntI[b];
    float s = 0.f;
    for (int k = g; k < m; k += G) {
        int n = order[s0 + k];
        s += xx[(size_t)n * C + c] * w[n];
    }
    red[threadIdx.x] = s;
    __syncthreads();
    for (int half = G / 2; half > 0; half >>= 1) {
        if (g < half) red[g * C + c] += red[(g + half) * C + c];
        __syncthreads();
    }
    if (g == 0) jet[b * C + c] = red[c];
}

// --------- fused1: shortcut GEMM + bn1+relu + @W1^T * w  -----------------
#define TILE1 32
__global__ __launch_bounds__(256) void fused1_kernel(const float* __restrict__ x,
                                                     const float* __restrict__ w,
                                                     const float* __restrict__ scale,
                                                     const float* __restrict__ shift,
                                                     const float* __restrict__ Wsc,
                                                     const float* __restrict__ W1,
                                                     unsigned short* __restrict__ hs,
                                                     float* __restrict__ out) {
    __shared__ __align__(16) float xs[TILE1][68];
    __shared__ __align__(16) float xn[TILE1][68];
    __shared__ __align__(16) float Wl[160][68];
    int tid = threadIdx.x;
    int n0  = blockIdx.x * TILE1;

    for (int i = tid; i < 128 * 64; i += 256) Wl[i >> 6][i & 63] = Wsc[i];
    for (int i = tid; i < 32 * 64;  i += 256) Wl[128 + (i >> 6)][i & 63] = W1[i];
    for (int i = tid; i < TILE1 * 64; i += 256) {
        int r = i >> 6, c = i & 63;
        int n = n0 + r;
        float v = (n < N_NODES) ? x[(size_t)n * 64 + c] : 0.f;
        xs[r][c] = v;
        float vn = v * scale[c] + shift[c];
        xn[r][c] = vn > 0.f ? vn : 0.f;
    }
    __syncthreads();

    int r0 = tid >> 4;
    int s  = tid & 15;
    float acc[2][10];
#pragma unroll
    for (int q = 0; q < 2; q++)
#pragma unroll
        for (int k = 0; k < 10; k++) acc[q][k] = 0.f;

    for (int c = 0; c < 64; c += 4) {
        float4 xr0 = *(const float4*)&xs[r0][c];
        float4 xr1 = *(const float4*)&xs[r0 + 16][c];
        float4 xn0 = *(const float4*)&xn[r0][c];
        float4 xn1 = *(const float4*)&xn[r0 + 16][c];
#pragma unroll
        for (int k = 0; k < 10; k++) {
            int row = (k < 8) ? (s + 16 * k) : (128 + s + 16 * (k - 8));
            float4 wv = *(const float4*)&Wl[row][c];
            float4 a0 = (k < 8) ? xr0 : xn0;
            float4 a1 = (k < 8) ? xr1 : xn1;
            acc[0][k] += a0.x * wv.x + a0.y * wv.y + a0.z * wv.z + a0.w * wv.w;
            acc[1][k] += a1.x * wv.x + a1.y * wv.y + a1.z * wv.z + a1.w * wv.w;
        }
    }
#pragma unroll
    for (int q = 0; q < 2; q++) {
        int n = n0 + r0 + 16 * q;
        if (n < N_NODES) {
            float ww = w[n];
#pragma unroll
            for (int k = 0; k < 8; k++) out[(size_t)n * 128 + s + 16 * k] = acc[q][k];
            hs[n * 32 + s]      = f2bf(acc[q][8] * ww);
            hs[n * 32 + s + 16] = f2bf(acc[q][9] * ww);
        }
    }
}

// ---------- gather: one wave per node, lane = channel pair ---------------
template<int PRE>
__global__ __launch_bounds__(256) void gather2_kernel(const int* __restrict__ base,
                                                      const int* __restrict__ cnt,
                                                      const int* __restrict__ tail_s,
                                                      const float* __restrict__ pf_s,
                                                      const int* __restrict__ eid,
                                                      const int* __restrict__ tail,
                                                      const float* __restrict__ pf,
                                                      const unsigned short* __restrict__ hs,
                                                      float* __restrict__ agg) {
    int n = blockIdx.x * 4 + (threadIdx.x >> 6);
    if (n >= N_NODES) return;
    int lane = threadIdx.x & 63;
    int i = lane >> 1;
    int th = (lane & 1) * 2;
    int s0 = base[n], c = cnt[n];
    float a0 = 0.f, a1 = 0.f;
    int k = 0;
    for (; k + 4 <= c; k += 4) {
        int t0, t1, t2, t3;
        float2 p0, p1, p2, p3;
        if (PRE) {
            t0 = tail_s[s0 + k];     t1 = tail_s[s0 + k + 1];
            t2 = tail_s[s0 + k + 2]; t3 = tail_s[s0 + k + 3];
            p0 = *(const float2*)&pf_s[(size_t)(s0 + k) * 4 + th];
            p1 = *(const float2*)&pf_s[(size_t)(s0 + k + 1) * 4 + th];
            p2 = *(const float2*)&pf_s[(size_t)(s0 + k + 2) * 4 + th];
            p3 = *(const float2*)&pf_s[(size_t)(s0 + k + 3) * 4 + th];
        } else {
            int e0 = eid[s0 + k],     e1 = eid[s0 + k + 1];
            int e2 = eid[s0 + k + 2], e3 = eid[s0 + k + 3];
            t0 = tail[e0]; t1 = tail[e1]; t2 = tail[e2]; t3 = tail[e3];
            p0 = *(const float2*)&pf[(size_t)e0 * 4 + th];
            p1 = *(const float2*)&pf[(size_t)e1 * 4 + th];
            p2 = *(const float2*)&pf[(size_t)e2 * 4 + th];
            p3 = *(const float2*)&pf[(size_t)e3 * 4 + th];
        }
        float h0 = bf2f(hs[(size_t)t0 * 32 + i]);
        float h1 = bf2f(hs[(size_t)t1 * 32 + i]);
        float h2 = bf2f(hs[(size_t)t2 * 32 + i]);
        float h3 = bf2f(hs[(size_t)t3 * 32 + i]);
        a0 += h0 * p0.x; a1 += h0 * p0.y;
        a0 += h1 * p1.x; a1 += h1 * p1.y;
        a0 += h2 * p2.x; a1 += h2 * p2.y;
        a0 += h3 * p3.x; a1 += h3 * p3.y;
    }
    for (; k < c; k++) {
        int t0; float2 p0;
        if (PRE) {
            t0 = tail_s[s0 + k];
            p0 = *(const float2*)&pf_s[(size_t)(s0 + k) * 4 + th];
        } else {
            int e0 = eid[s0 + k];
            t0 = tail[e0];
            p0 = *(const float2*)&pf[(size_t)e0 * 4 + th];
        }
        float h0 = bf2f(hs[(size_t)t0 * 32 + i]);
        a0 += h0 * p0.x; a1 += h0 * p0.y;
    }
    *(float2*)&agg[(size_t)n * 128 + lane * 2] = make_float2(a0, a1);
}

// -------- legacy atomic edge scatter (ultimate fallback) -----------------
__global__ __launch_bounds__(256) void edge_kernel(const int* __restrict__ head,
                                                   const int* __restrict__ tail,
                                                   const float* __restrict__ pf,
                                                   const unsigned short* __restrict__ hs,
                                                   float* __restrict__ agg) {
    long long tid = (long long)blockIdx.x * 256 + threadIdx.x;
    if (tid >= (long long)N_EDGES * 128) return;
    int e = (int)(tid >> 7);
    int j = (int)(tid & 127);
    int i = j >> 2, t = j & 3;
    float v = bf2f(hs[(size_t)tail[e] * 32 + i]) * pf[(size_t)e * 4 + t];
    atomicAdd(&agg[(size_t)head[e] * 128 + j], v);
}

// ------- fused2: y = relu(bn(x)) @ W^T (+resid), 64-row tile, 4x4 reg ----
#define TILE2 64
__global__ __launch_bounds__(256) void fused2_kernel(const float* __restrict__ xin,
                                                     const float* __restrict__ scale,
                                                     const float* __restrict__ shift,
                                                     const float* __restrict__ W,
                                                     float* __restrict__ yout,
                                                     const float* __restrict__ resid) {
    __shared__ __align__(16) float xn[TILE2][128];   // swizzled c ^= (r&3)<<2
    __shared__ __align__(16) float Wl[64][128];      // swizzled c ^= (r&7)<<2
    int tid = threadIdx.x;
    int n0  = blockIdx.x * TILE2;

    for (int idx = tid; idx < TILE2 * 32; idx += 256) {
        int r = idx >> 5, c = (idx & 31) << 2;
        int n = n0 + r;
        float4 v = make_float4(0.f, 0.f, 0.f, 0.f);
        if (n < N_NODES) v = *(const float4*)&xin[(size_t)n * 128 + c];
        float4 sc = *(const float4*)&scale[c];
        float4 sh = *(const float4*)&shift[c];
        float4 o;
        o.x = fmaxf(fmaf(v.x, sc.x, sh.x), 0.f);
        o.y = fmaxf(fmaf(v.y, sc.y, sh.y), 0.f);
        o.z = fmaxf(fmaf(v.z, sc.z, sh.z), 0.f);
        o.w = fmaxf(fmaf(v.w, sc.w, sh.w), 0.f);
        *(float4*)&xn[r][c ^ ((r & 3) << 2)] = o;
    }
    for (int idx = tid; idx < 64 * 32; idx += 256) {
        int r = idx >> 5, c = (idx & 31) << 2;
        *(float4*)&Wl[r][c ^ ((r & 7) << 2)] = *(const float4*)&W[r * 128 + c];
    }
    __syncthreads();

    int r0 = tid >> 4;
    int s  = tid & 15;
    float accA[4][4], accB[4][4];
#pragma unroll
    for (int q = 0; q < 4; q++)
#pragma unroll
        for (int k = 0; k < 4; k++) accA[q][k] = 0.f;

    for (int c = 0; c < 128; c += 4) {
        float4 xv[4];
#pragma unroll
        for (int q = 0; q < 4; q++) {
            int r = r0 + (q << 4);
            xv[q] = *(const float4*)&xn[r][c ^ ((r & 3) << 2)];
        }
#pragma unroll
        for (int k = 0; k < 4; k++) {
            int row = s + (k << 4);
            float4 wv = *(const float4*)&Wl[row][c ^ ((row & 7) << 2)];
#pragma unroll
            for (int q = 0; q < 4; q++)
                accA[q][k] += xv[q].x * wv.x + xv[q].y * wv.y + xv[q].z * wv.z + xv[q].w * wv.w;
        }
    }
    __syncthreads();
    for (int idx = tid; idx < 64 * 32; idx += 256) {
        int r = idx >> 5, c = (idx & 31) << 2;
        *(float4*)&Wl[r][c ^ ((r & 7) << 2)] = *(const float4*)&W[(64 + r) * 128 + c];
    }
    __syncthreads();
#pragma unroll
    for (int q = 0; q < 4; q++)
#pragma unroll
        for (int k = 0; k < 4; k++) accB[q][k] = 0.f;

    for (int c = 0; c < 128; c += 4) {
        float4 xv[4];
#pragma unroll
        for (int q = 0; q < 4; q++) {
            int r = r0 + (q << 4);
            xv[q] = *(const float4*)&xn[r][c ^ ((r & 3) << 2)];
        }
#pragma unroll
        for (int k = 0; k < 4; k++) {
            int row = s + (k << 4);
            float4 wv = *(const float4*)&Wl[row][c ^ ((row & 7) << 2)];
#pragma unroll
            for (int q = 0; q < 4; q++)
                accB[q][k] += xv[q].x * wv.x + xv[q].y * wv.y + xv[q].z * wv.z + xv[q].w * wv.w;
        }
    }
#pragma unroll
    for (int q = 0; q < 4; q++) {
        int n = n0 + r0 + (q << 4);
        if (n < N_NODES) {
#pragma unroll
            for (int k = 0; k < 4; k++) {
                int oA = s + (k << 4), oB = 64 + oA;
                float vA = accA[q][k], vB = accB[q][k];
                if (resid) {
                    vA += resid[(size_t)n * 128 + oA];
                    vB += resid[(size_t)n * 128 + oB];
                }
                yout[(size_t)n * 128 + oA] = vA;
                yout[(size_t)n * 128 + oB] = vB;
            }
        }
    }
}

extern "C" void kernel_launch(void* const* d_in, const int* in_sizes, int n_in,
                              void* d_out, int out_size, void* d_ws, size_t ws_size,
                              hipStream_t stream) {
    const float* x    = (const float*)d_in[0];
    const float* w    = (const float*)d_in[1];
    const float* pf   = (const float*)d_in[2];
    const int*   head = (const int*)d_in[3];
    const int*   tail = (const int*)d_in[4];
    const int*   ind  = (const int*)d_in[5];
    const float* Wsc  = (const float*)d_in[6];
    const float* g1   = (const float*)d_in[7];
    const float* b1   = (const float*)d_in[8];
    const float* W1   = (const float*)d_in[9];
    const float* g2   = (const float*)d_in[10];
    const float* b2   = (const float*)d_in[11];
    const float* W2   = (const float*)d_in[12];
    const float* g3   = (const float*)d_in[13];
    const float* b3   = (const float*)d_in[14];
    const float* W3   = (const float*)d_in[15];
    float* out = (float*)d_out;

    char* p = (char*)d_ws;
    unsigned short* hs = (unsigned short*)p;  p += (size_t)N_NODES * 32 * 2;   // 6.4MB
    float* agg  = (float*)p;                  p += (size_t)N_NODES * 128 * 4;  // 51.2MB
    float* jet1 = (float*)p;                  p += 1024 * 64 * 4;
    float* jet2 = (float*)p;                  p += 1024 * 128 * 4;
    float* jet3 = (float*)p;                  p += 1024 * 128 * 4;
    float* sc1 = (float*)p; p += 64 * 4;  float* sh1 = (float*)p; p += 64 * 4;
    float* sc2 = (float*)p; p += 128 * 4; float* sh2 = (float*)p; p += 128 * 4;
    float* sc3 = (float*)p; p += 128 * 4; float* sh3 = (float*)p; p += 128 * 4;
    int* cnt_e    = (int*)p; p += (size_t)N_NODES * 4;
    int* base_e   = (int*)p; p += (size_t)N_NODES * 4;
    int* cursor_e = (int*)p; p += (size_t)N_NODES * 4;
    int* part     = (int*)p; p += 1024 * 4;
    int* cntI     = (int*)p; p += 1024 * 4;
    int* baseI    = (int*)p; p += 1024 * 4;
    int* cursorI  = (int*)p; p += 1024 * 4;
    int* order    = (int*)p; p += (size_t)N_NODES * 4;
    int* eid      = (int*)p; p += (size_t)N_EDGES * 4;       // 6.4MB
    size_t need_t2 = (size_t)(p - (char*)d_ws);
    int*   tail_s = (int*)p;   p += (size_t)N_EDGES * 4;     // 6.4MB
    float* pf_s   = (float*)p; p += (size_t)N_EDGES * 16;    // 25.6MB
    size_t need_t1 = (size_t)(p - (char*)d_ws);
    int tier = (ws_size >= need_t1) ? 1 : (ws_size >= need_t2) ? 2 : 3;

    // ---- indicator-CSR (atomic-free jets) ----
    hipMemsetAsync(cntI, 0, 1024 * sizeof(int), stream);
    countI_kernel<<<(N_NODES + 255) / 256, 256, 0, stream>>>(ind, cntI);
    scanB_kernel<<<1, 1024, 0, stream>>>(cntI, baseI, cursorI, 1024);
    scatterI_kernel<<<(N_NODES + 255) / 256, 256, 0, stream>>>(ind, cursorI, order);

    // ---- BN1 stats ----
    bucket_jet_kernel<64><<<1024, 256, 0, stream>>>(x, w, order, baseI, cntI, jet1);
    stats_kernel<64><<<64, 256, 0, stream>>>(jet1, g1, b1, sc1, sh1);

    // ---- shortcut + layer1 ----
    fused1_kernel<<<(N_NODES + TILE1 - 1) / TILE1, 256, 0, stream>>>(
        x, w, sc1, sh1, Wsc, W1, hs, out);

    // ---- edge message passing ----
    if (tier <= 2) {
        hipMemsetAsync(cnt_e, 0, N_NODES * sizeof(int), stream);
        count_head_kernel<<<(N_EDGES + 255) / 256, 256, 0, stream>>>(head, cnt_e);
        scanA_kernel<<<SNBLK, SCHUNK, 0, stream>>>(cnt_e, part, N_NODES);
        scanB_kernel<<<1, 1024, 0, stream>>>(part, part, nullptr, SNBLK);
        scanC_kernel<<<SNBLK, SCHUNK, 0, stream>>>(cnt_e, part, base_e, cursor_e, N_NODES);
        escatterE_kernel<<<(N_EDGES + 255) / 256, 256, 0, stream>>>(head, cursor_e, eid);
        if (tier == 1) {
            permute_kernel<<<(N_EDGES + 255) / 256, 256, 0, stream>>>(
                eid, tail, pf, tail_s, pf_s);
            gather2_kernel<1><<<(N_NODES + 3) / 4, 256, 0, stream>>>(
                base_e, cnt_e, tail_s, pf_s, nullptr, tail, pf, hs, agg);
        } else {
            gather2_kernel<0><<<(N_NODES + 3) / 4, 256, 0, stream>>>(
                base_e, cnt_e, nullptr, nullptr, eid, tail, pf, hs, agg);
        }
    } else {
        hipMemsetAsync(agg, 0, (size_t)N_NODES * 128 * sizeof(float), stream);
        edge_kernel<<<(int)(((long long)N_EDGES * 128) / 256), 256, 0, stream>>>(
            head, tail, pf, hs, agg);
    }

    // ---- BN2 + layer2 (in place on agg) ----
    bucket_jet_kernel<128><<<1024, 256, 0, stream>>>(agg, w, order, baseI, cntI, jet2);
    stats_kernel<128><<<128, 256, 0, stream>>>(jet2, g2, b2, sc2, sh2);
    fused2_kernel<<<(N_NODES + TILE2 - 1) / TILE2, 256, 0, stream>>>(
        agg, sc2, sh2, W2, agg, nullptr);

    // ---- BN3 + layer3 + shortcut add ----
    bucket_jet_kernel<128><<<1024, 256, 0, stream>>>(agg, w, order, baseI, cntI, jet3);
    stats_kernel<128><<<128, 256, 0, stream>>>(jet3, g3, b3, sc3, sh3);
    fused2_kernel<<<(N_NODES + TILE2 - 1) / TILE2, 256, 0, stream>>>(
        agg, sc3, sh3, W3, out, out);

    (void)in_sizes; (void)n_in; (void)out_size;
}

// Round 6
// 646.268 us; speedup vs baseline: 1.1247x; 1.1018x over previous
//
#include <hip/hip_runtime.h>

#define N_NODES 100000
#define N_EDGES 1600000
#define NB      1024
#define EPSF    1e-5f

#define SCHUNK 128
#define SNBLK ((N_NODES + SCHUNK - 1) / SCHUNK)   // 782

#define BUK_SH  7
#define NBUK    ((N_NODES + 127) >> 7)            // 782 buckets of 128 heads
#define EPB     16384
#define NBA     ((N_EDGES + EPB - 1) / EPB)       // 98 binning blocks
#define NCB     (NBUK * NBA)                      // 76,636 count-matrix entries
#define SNB2    ((NCB + SCHUNK - 1) / SCHUNK)     // 599

__device__ __forceinline__ float bf2f(unsigned short u) {
    union { unsigned int i; float f; } v; v.i = ((unsigned int)u) << 16; return v.f;
}
__device__ __forceinline__ unsigned short f2bf(float f) {
    union { float ff; unsigned int i; } v; v.ff = f;
    unsigned int r = v.i + 0x7FFFu + ((v.i >> 16) & 1u);   // RNE
    return (unsigned short)(r >> 16);
}

// -------------- per-channel mean/var(ddof=1) -> scale/shift --------------
template<int C>
__global__ __launch_bounds__(256) void stats_kernel(const float* __restrict__ jet,
                                                    const float* __restrict__ g,
                                                    const float* __restrict__ b,
                                                    float* __restrict__ scale,
                                                    float* __restrict__ shift) {
    int c = blockIdx.x;
    int t = threadIdx.x;
    float s = 0.f, s2 = 0.f;
    for (int r = t; r < NB; r += 256) {
        float v = jet[r * C + c];
        s += v; s2 += v * v;
    }
    __shared__ float ls[256], ls2[256];
    ls[t] = s; ls2[t] = s2;
    __syncthreads();
    for (int ofs = 128; ofs > 0; ofs >>= 1) {
        if (t < ofs) { ls[t] += ls[t + ofs]; ls2[t] += ls2[t + ofs]; }
        __syncthreads();
    }
    if (t == 0) {
        float mean = ls[0] / (float)NB;
        float var  = (ls2[0] - (float)NB * mean * mean) / (float)(NB - 1);
        float sc   = g[c] / sqrtf(var + EPSF);
        scale[c] = sc;
        shift[c] = b[c] - mean * sc;
    }
}

// ---------------- count kernels ------------------------------------------
__global__ __launch_bounds__(256) void count_head_kernel(const int* __restrict__ head,
                                                         int* __restrict__ cnt) {
    int e = blockIdx.x * 256 + threadIdx.x;
    if (e < N_EDGES) atomicAdd(&cnt[head[e]], 1);
}
__global__ __launch_bounds__(256) void countI_kernel(const int* __restrict__ ind,
                                                     int* __restrict__ cntI) {
    int n = blockIdx.x * 256 + threadIdx.x;
    if (n < N_NODES) atomicAdd(&cntI[ind[n]], 1);
}

// ---------------- scans ---------------------------------------------------
__global__ __launch_bounds__(SCHUNK) void scanA_kernel(const int* __restrict__ cnt,
                                                       int* __restrict__ part, int n) {
    __shared__ int ls[SCHUNK];
    int t = threadIdx.x;
    int i = blockIdx.x * SCHUNK + t;
    ls[t] = (i < n) ? cnt[i] : 0;
    __syncthreads();
    for (int ofs = SCHUNK / 2; ofs > 0; ofs >>= 1) {
        if (t < ofs) ls[t] += ls[t + ofs];
        __syncthreads();
    }
    if (t == 0) part[blockIdx.x] = ls[0];
}

// single-block scan (n <= 1024); EXCLUSIVE prefix to out (and out2)
__global__ __launch_bounds__(1024) void scanB_kernel(const int* __restrict__ in,
                                                     int* __restrict__ out,
                                                     int* __restrict__ out2, int n) {
    __shared__ int ls[1024];
    int t = threadIdx.x;
    int v = (t < n) ? in[t] : 0;
    ls[t] = v;
    __syncthreads();
    for (int ofs = 1; ofs < 1024; ofs <<= 1) {
        int u = (t >= ofs) ? ls[t - ofs] : 0;
        __syncthreads();
        ls[t] += u;
        __syncthreads();
    }
    if (t < n) {
        int e = ls[t] - v;
        out[t] = e;
        if (out2) out2[t] = e;
    }
}

__global__ __launch_bounds__(SCHUNK) void scanC_kernel(const int* __restrict__ cnt,
                                                       const int* __restrict__ poff,
                                                       int* __restrict__ base,
                                                       int* __restrict__ cursor, int n) {
    __shared__ int ls[SCHUNK];
    int t = threadIdx.x;
    int i = blockIdx.x * SCHUNK + t;
    int v = (i < n) ? cnt[i] : 0;
    ls[t] = v;
    __syncthreads();
    for (int ofs = 1; ofs < SCHUNK; ofs <<= 1) {
        int u = (t >= ofs) ? ls[t - ofs] : 0;
        __syncthreads();
        ls[t] += u;
        __syncthreads();
    }
    if (i < n) {
        int bse = poff[blockIdx.x] + ls[t] - v;
        base[i] = bse;
        cursor[i] = bse;
    }
}

// ---- Pass A: per-(bucket, block) histogram, bucket-major output ---------
__global__ __launch_bounds__(256) void countCB_kernel(const int* __restrict__ head,
                                                      int* __restrict__ cnt_cb) {
    __shared__ int h[NBUK];
    int tid = threadIdx.x;
    int blk = blockIdx.x;
    for (int i = tid; i < NBUK; i += 256) h[i] = 0;
    __syncthreads();
    int e0 = blk * EPB;
    for (int k = tid; k < EPB; k += 256) {
        int e = e0 + k;
        if (e < N_EDGES) atomicAdd(&h[head[e] >> BUK_SH], 1);
    }
    __syncthreads();
    for (int i = tid; i < NBUK; i += 256) cnt_cb[i * NBA + blk] = h[i];
}

// ---- Pass C: bin packed records (eid | head_low<<21) into bucket chunks --
__global__ __launch_bounds__(256) void binC_kernel(const int* __restrict__ head,
                                                   const int* __restrict__ cbase,
                                                   unsigned* __restrict__ hb) {
    __shared__ int cur[NBUK];
    int tid = threadIdx.x;
    int blk = blockIdx.x;
    for (int i = tid; i < NBUK; i += 256) cur[i] = cbase[i * NBA + blk];
    __syncthreads();
    int e0 = blk * EPB;
    for (int k = tid; k < EPB; k += 256) {
        int e = e0 + k;
        if (e < N_EDGES) {
            int hd = head[e];
            int b = hd >> BUK_SH;
            int slot = atomicAdd(&cur[b], 1);
            hb[slot] = (unsigned)e | ((unsigned)(hd & 127) << 21);
        }
    }
}

// ---- Pass D: within-bucket CSR placement; random READS, clean writes ----
__global__ __launch_bounds__(256) void sortD_kernel(const int* __restrict__ cbase,
                                                    const int* __restrict__ base_e,
                                                    const unsigned* __restrict__ hb,
                                                    const int* __restrict__ tail,
                                                    const float* __restrict__ pf,
                                                    int* __restrict__ tail_s,
                                                    float* __restrict__ pf_s) {
    __shared__ int hcur[128];
    int tid = threadIdx.x;
    int b = blockIdx.x;
    int h0 = b << BUK_SH;
    if (tid < 128) {
        int h = h0 + tid;
        hcur[tid] = (h < N_NODES) ? base_e[h] : 0;
    }
    __syncthreads();
    int lo = cbase[b * NBA];
    int hi = (b + 1 < NBUK) ? cbase[(b + 1) * NBA] : N_EDGES;
    for (int k = lo + tid; k < hi; k += 256) {
        unsigned rec = hb[k];
        int e = (int)(rec & 0x1FFFFFu);
        int h7 = (int)(rec >> 21);
        int slot = atomicAdd(&hcur[h7], 1);
        tail_s[slot] = tail[e];
        ((float4*)pf_s)[slot] = ((const float4*)pf)[e];
    }
}

// ---------------- legacy scatter (tier-2 fallback) -----------------------
__global__ __launch_bounds__(256) void escatterE_kernel(const int* __restrict__ head,
                                                        int* __restrict__ cursor,
                                                        int* __restrict__ eid) {
    int e = blockIdx.x * 256 + threadIdx.x;
    if (e >= N_EDGES) return;
    int slot = atomicAdd(&cursor[head[e]], 1);
    eid[slot] = e;
}

__global__ __launch_bounds__(256) void scatterI_kernel(const int* __restrict__ ind,
                                                       int* __restrict__ cursorI,
                                                       int* __restrict__ order) {
    int n = blockIdx.x * 256 + threadIdx.x;
    if (n < N_NODES) {
        int pos = atomicAdd(&cursorI[ind[n]], 1);
        order[pos] = n;
    }
}

// ---------- bucket jet: jet[b,c] = sum_{n in bucket b} x[n,c]*w[n] -------
template<int C>
__global__ __launch_bounds__(256) void bucket_jet_kernel(const float* __restrict__ xx,
                                                         const float* __restrict__ w,
                                                         const int* __restrict__ order,
                                                         const int* __restrict__ baseI,
                                                         const int* __restrict__ cntI,
                                                         float* __restrict__ jet) {
    constexpr int G = 256 / C;
    __shared__ float red[256];
    int b = blockIdx.x;
    int g = threadIdx.x / C;
    int c = threadIdx.x % C;
    int s0 = baseI[b], m = cntI[b];
    float s = 0.f;
    for (int k = g; k < m; k += G) {
        int n = order[s0 + k];
        s += xx[(size_t)n * C + c] * w[n];
    }
    red[threadIdx.x] = s;
    __syncthreads();
    for (int half = G / 2; half > 0; half >>= 1) {
        if (g < half) red[g * C + c] += red[(g + half) * C + c];
        __syncthreads();
    }
    if (g == 0) jet[b * C + c] = red[c];
}

// --------- fused1: shortcut GEMM + bn1+relu + @W1^T * w  -----------------
#define TILE1 32
__global__ __launch_bounds__(256) void fused1_kernel(const float* __restrict__ x,
                                                     const float* __restrict__ w,
                                                     const float* __restrict__ scale,
                                                     const float* __restrict__ shift,
                                                     const float* __restrict__ Wsc,
                                                     const float* __restrict__ W1,
                                                     unsigned short* __restrict__ hs,
                                                     float* __restrict__ out) {
    __shared__ __align__(16) float xs[TILE1][68];
    __shared__ __align__(16) float xn[TILE1][68];
    __shared__ __align__(16) float Wl[160][68];
    int tid = threadIdx.x;
    int n0  = blockIdx.x * TILE1;

    for (int i = tid; i < 128 * 64; i += 256) Wl[i >> 6][i & 63] = Wsc[i];
    for (int i = tid; i < 32 * 64;  i += 256) Wl[128 + (i >> 6)][i & 63] = W1[i];
    for (int i = tid; i < TILE1 * 64; i += 256) {
        int r = i >> 6, c = i & 63;
        int n = n0 + r;
        float v = (n < N_NODES) ? x[(size_t)n * 64 + c] : 0.f;
        xs[r][c] = v;
        float vn = v * scale[c] + shift[c];
        xn[r][c] = vn > 0.f ? vn : 0.f;
    }
    __syncthreads();

    int r0 = tid >> 4;
    int s  = tid & 15;
    float acc[2][10];
#pragma unroll
    for (int q = 0; q < 2; q++)
#pragma unroll
        for (int k = 0; k < 10; k++) acc[q][k] = 0.f;

    for (int c = 0; c < 64; c += 4) {
        float4 xr0 = *(const float4*)&xs[r0][c];
        float4 xr1 = *(const float4*)&xs[r0 + 16][c];
        float4 xn0 = *(const float4*)&xn[r0][c];
        float4 xn1 = *(const float4*)&xn[r0 + 16][c];
#pragma unroll
        for (int k = 0; k < 10; k++) {
            int row = (k < 8) ? (s + 16 * k) : (128 + s + 16 * (k - 8));
            float4 wv = *(const float4*)&Wl[row][c];
            float4 a0 = (k < 8) ? xr0 : xn0;
            float4 a1 = (k < 8) ? xr1 : xn1;
            acc[0][k] += a0.x * wv.x + a0.y * wv.y + a0.z * wv.z + a0.w * wv.w;
            acc[1][k] += a1.x * wv.x + a1.y * wv.y + a1.z * wv.z + a1.w * wv.w;
        }
    }
#pragma unroll
    for (int q = 0; q < 2; q++) {
        int n = n0 + r0 + 16 * q;
        if (n < N_NODES) {
            float ww = w[n];
#pragma unroll
            for (int k = 0; k < 8; k++) out[(size_t)n * 128 + s + 16 * k] = acc[q][k];
            hs[n * 32 + s]      = f2bf(acc[q][8] * ww);
            hs[n * 32 + s + 16] = f2bf(acc[q][9] * ww);
        }
    }
}

// ---------- gather: one wave per node, lane = channel pair ---------------
template<int PRE>
__global__ __launch_bounds__(256) void gather2_kernel(const int* __restrict__ base,
                                                      const int* __restrict__ cnt,
                                                      const int* __restrict__ tail_s,
                                                      const float* __restrict__ pf_s,
                                                      const int* __restrict__ eid,
                                                      const int* __restrict__ tail,
                                                      const float* __restrict__ pf,
                                                      const unsigned short* __restrict__ hs,
                                                      float* __restrict__ agg) {
    int n = blockIdx.x * 4 + (threadIdx.x >> 6);
    if (n >= N_NODES) return;
    int lane = threadIdx.x & 63;
    int i = lane >> 1;
    int th = (lane & 1) * 2;
    int s0 = base[n], c = cnt[n];
    float a0 = 0.f, a1 = 0.f;
    int k = 0;
    for (; k + 4 <= c; k += 4) {
        int t0, t1, t2, t3;
        float2 p0, p1, p2, p3;
        if (PRE) {
            t0 = tail_s[s0 + k];     t1 = tail_s[s0 + k + 1];
            t2 = tail_s[s0 + k + 2]; t3 = tail_s[s0 + k + 3];
            p0 = *(const float2*)&pf_s[(size_t)(s0 + k) * 4 + th];
            p1 = *(const float2*)&pf_s[(size_t)(s0 + k + 1) * 4 + th];
            p2 = *(const float2*)&pf_s[(size_t)(s0 + k + 2) * 4 + th];
            p3 = *(const float2*)&pf_s[(size_t)(s0 + k + 3) * 4 + th];
        } else {
            int e0 = eid[s0 + k],     e1 = eid[s0 + k + 1];
            int e2 = eid[s0 + k + 2], e3 = eid[s0 + k + 3];
            t0 = tail[e0]; t1 = tail[e1]; t2 = tail[e2]; t3 = tail[e3];
            p0 = *(const float2*)&pf[(size_t)e0 * 4 + th];
            p1 = *(const float2*)&pf[(size_t)e1 * 4 + th];
            p2 = *(const float2*)&pf[(size_t)e2 * 4 + th];
            p3 = *(const float2*)&pf[(size_t)e3 * 4 + th];
        }
        float h0 = bf2f(hs[(size_t)t0 * 32 + i]);
        float h1 = bf2f(hs[(size_t)t1 * 32 + i]);
        float h2 = bf2f(hs[(size_t)t2 * 32 + i]);
        float h3 = bf2f(hs[(size_t)t3 * 32 + i]);
        a0 += h0 * p0.x; a1 += h0 * p0.y;
        a0 += h1 * p1.x; a1 += h1 * p1.y;
        a0 += h2 * p2.x; a1 += h2 * p2.y;
        a0 += h3 * p3.x; a1 += h3 * p3.y;
    }
    for (; k < c; k++) {
        int t0; float2 p0;
        if (PRE) {
            t0 = tail_s[s0 + k];
            p0 = *(const float2*)&pf_s[(size_t)(s0 + k) * 4 + th];
        } else {
            int e0 = eid[s0 + k];
            t0 = tail[e0];
            p0 = *(const float2*)&pf[(size_t)e0 * 4 + th];
        }
        float h0 = bf2f(hs[(size_t)t0 * 32 + i]);
        a0 += h0 * p0.x; a1 += h0 * p0.y;
    }
    *(float2*)&agg[(size_t)n * 128 + lane * 2] = make_float2(a0, a1);
}

// -------- legacy atomic edge scatter (ultimate fallback) -----------------
__global__ __launch_bounds__(256) void edge_kernel(const int* __restrict__ head,
                                                   const int* __restrict__ tail,
                                                   const float* __restrict__ pf,
                                                   const unsigned short* __restrict__ hs,
                                                   float* __restrict__ agg) {
    long long tid = (long long)blockIdx.x * 256 + threadIdx.x;
    if (tid >= (long long)N_EDGES * 128) return;
    int e = (int)(tid >> 7);
    int j = (int)(tid & 127);
    int i = j >> 2, t = j & 3;
    float v = bf2f(hs[(size_t)tail[e] * 32 + i]) * pf[(size_t)e * 4 + t];
    atomicAdd(&agg[(size_t)head[e] * 128 + j], v);
}

// ------- fused2: y = relu(bn(x)) @ W^T (+resid), 64-row tile, 4x4 reg ----
#define TILE2 64
__global__ __launch_bounds__(256) void fused2_kernel(const float* __restrict__ xin,
                                                     const float* __restrict__ scale,
                                                     const float* __restrict__ shift,
                                                     const float* __restrict__ W,
                                                     float* __restrict__ yout,
                                                     const float* __restrict__ resid) {
    __shared__ __align__(16) float xn[TILE2][128];   // swizzled c ^= (r&3)<<2
    __shared__ __align__(16) float Wl[64][128];      // swizzled c ^= (r&7)<<2
    int tid = threadIdx.x;
    int n0  = blockIdx.x * TILE2;

    for (int idx = tid; idx < TILE2 * 32; idx += 256) {
        int r = idx >> 5, c = (idx & 31) << 2;
        int n = n0 + r;
        float4 v = make_float4(0.f, 0.f, 0.f, 0.f);
        if (n < N_NODES) v = *(const float4*)&xin[(size_t)n * 128 + c];
        float4 sc = *(const float4*)&scale[c];
        float4 sh = *(const float4*)&shift[c];
        float4 o;
        o.x = fmaxf(fmaf(v.x, sc.x, sh.x), 0.f);
        o.y = fmaxf(fmaf(v.y, sc.y, sh.y), 0.f);
        o.z = fmaxf(fmaf(v.z, sc.z, sh.z), 0.f);
        o.w = fmaxf(fmaf(v.w, sc.w, sh.w), 0.f);
        *(float4*)&xn[r][c ^ ((r & 3) << 2)] = o;
    }
    for (int idx = tid; idx < 64 * 32; idx += 256) {
        int r = idx >> 5, c = (idx & 31) << 2;
        *(float4*)&Wl[r][c ^ ((r & 7) << 2)] = *(const float4*)&W[r * 128 + c];
    }
    __syncthreads();

    int r0 = tid >> 4;
    int s  = tid & 15;
    float accA[4][4], accB[4][4];
#pragma unroll
    for (int q = 0; q < 4; q++)
#pragma unroll
        for (int k = 0; k < 4; k++) accA[q][k] = 0.f;

    for (int c = 0; c < 128; c += 4) {
        float4 xv[4];
#pragma unroll
        for (int q = 0; q < 4; q++) {
            int r = r0 + (q << 4);
            xv[q] = *(const float4*)&xn[r][c ^ ((r & 3) << 2)];
        }
#pragma unroll
        for (int k = 0; k < 4; k++) {
            int row = s + (k << 4);
            float4 wv = *(const float4*)&Wl[row][c ^ ((row & 7) << 2)];
#pragma unroll
            for (int q = 0; q < 4; q++)
                accA[q][k] += xv[q].x * wv.x + xv[q].y * wv.y + xv[q].z * wv.z + xv[q].w * wv.w;
        }
    }
    __syncthreads();
    for (int idx = tid; idx < 64 * 32; idx += 256) {
        int r = idx >> 5, c = (idx & 31) << 2;
        *(float4*)&Wl[r][c ^ ((r & 7) << 2)] = *(const float4*)&W[(64 + r) * 128 + c];
    }
    __syncthreads();
#pragma unroll
    for (int q = 0; q < 4; q++)
#pragma unroll
        for (int k = 0; k < 4; k++) accB[q][k] = 0.f;

    for (int c = 0; c < 128; c += 4) {
        float4 xv[4];
#pragma unroll
        for (int q = 0; q < 4; q++) {
            int r = r0 + (q << 4);
            xv[q] = *(const float4*)&xn[r][c ^ ((r & 3) << 2)];
        }
#pragma unroll
        for (int k = 0; k < 4; k++) {
            int row = s + (k << 4);
            float4 wv = *(const float4*)&Wl[row][c ^ ((row & 7) << 2)];
#pragma unroll
            for (int q = 0; q < 4; q++)
                accB[q][k] += xv[q].x * wv.x + xv[q].y * wv.y + xv[q].z * wv.z + xv[q].w * wv.w;
        }
    }
#pragma unroll
    for (int q = 0; q < 4; q++) {
        int n = n0 + r0 + (q << 4);
        if (n < N_NODES) {
#pragma unroll
            for (int k = 0; k < 4; k++) {
                int oA = s + (k << 4), oB = 64 + oA;
                float vA = accA[q][k], vB = accB[q][k];
                if (resid) {
                    vA += resid[(size_t)n * 128 + oA];
                    vB += resid[(size_t)n * 128 + oB];
                }
                yout[(size_t)n * 128 + oA] = vA;
                yout[(size_t)n * 128 + oB] = vB;
            }
        }
    }
}

extern "C" void kernel_launch(void* const* d_in, const int* in_sizes, int n_in,
                              void* d_out, int out_size, void* d_ws, size_t ws_size,
                              hipStream_t stream) {
    const float* x    = (const float*)d_in[0];
    const float* w    = (const float*)d_in[1];
    const float* pf   = (const float*)d_in[2];
    const int*   head = (const int*)d_in[3];
    const int*   tail = (const int*)d_in[4];
    const int*   ind  = (const int*)d_in[5];
    const float* Wsc  = (const float*)d_in[6];
    const float* g1   = (const float*)d_in[7];
    const float* b1   = (const float*)d_in[8];
    const float* W1   = (const float*)d_in[9];
    const float* g2   = (const float*)d_in[10];
    const float* b2   = (const float*)d_in[11];
    const float* W2   = (const float*)d_in[12];
    const float* g3   = (const float*)d_in[13];
    const float* b3   = (const float*)d_in[14];
    const float* W3   = (const float*)d_in[15];
    float* out = (float*)d_out;

    char* p = (char*)d_ws;
    unsigned short* hs = (unsigned short*)p;  p += (size_t)N_NODES * 32 * 2;   // 6.4MB
    float* agg  = (float*)p;                  p += (size_t)N_NODES * 128 * 4;  // 51.2MB
    float* jet1 = (float*)p;                  p += 1024 * 64 * 4;
    float* jet2 = (float*)p;                  p += 1024 * 128 * 4;
    float* jet3 = (float*)p;                  p += 1024 * 128 * 4;
    float* sc1 = (float*)p; p += 64 * 4;  float* sh1 = (float*)p; p += 64 * 4;
    float* sc2 = (float*)p; p += 128 * 4; float* sh2 = (float*)p; p += 128 * 4;
    float* sc3 = (float*)p; p += 128 * 4; float* sh3 = (float*)p; p += 128 * 4;
    int* cnt_e    = (int*)p; p += (size_t)N_NODES * 4;
    int* base_e   = (int*)p; p += (size_t)N_NODES * 4;
    int* cursor_e = (int*)p; p += (size_t)N_NODES * 4;
    int* part     = (int*)p; p += 1024 * 4;
    int* cntI     = (int*)p; p += 1024 * 4;
    int* baseI    = (int*)p; p += 1024 * 4;
    int* cursorI  = (int*)p; p += 1024 * 4;
    int* order    = (int*)p; p += (size_t)N_NODES * 4;
    unsigned* hb  = (unsigned*)p; p += (size_t)N_EDGES * 4;   // 6.4MB (tier2: eid)
    size_t need_t2 = (size_t)(p - (char*)d_ws);
    int* cnt_cb   = (int*)p; p += (size_t)NCB * 4;            // 307KB
    int* cbase    = (int*)p; p += (size_t)NCB * 4;
    int* ccur     = (int*)p; p += (size_t)NCB * 4;
    int*   tail_s = (int*)p;   p += (size_t)N_EDGES * 4;      // 6.4MB
    float* pf_s   = (float*)p; p += (size_t)N_EDGES * 16;     // 25.6MB
    size_t need_t1 = (size_t)(p - (char*)d_ws);
    int tier = (ws_size >= need_t1) ? 1 : (ws_size >= need_t2) ? 2 : 3;

    // ---- indicator-CSR (atomic-free jets) ----
    hipMemsetAsync(cntI, 0, 1024 * sizeof(int), stream);
    countI_kernel<<<(N_NODES + 255) / 256, 256, 0, stream>>>(ind, cntI);
    scanB_kernel<<<1, 1024, 0, stream>>>(cntI, baseI, cursorI, 1024);
    scatterI_kernel<<<(N_NODES + 255) / 256, 256, 0, stream>>>(ind, cursorI, order);

    // ---- BN1 stats ----
    bucket_jet_kernel<64><<<1024, 256, 0, stream>>>(x, w, order, baseI, cntI, jet1);
    stats_kernel<64><<<64, 256, 0, stream>>>(jet1, g1, b1, sc1, sh1);

    // ---- shortcut + layer1 ----
    fused1_kernel<<<(N_NODES + TILE1 - 1) / TILE1, 256, 0, stream>>>(
        x, w, sc1, sh1, Wsc, W1, hs, out);

    // ---- edge message passing ----
    if (tier <= 2) {
        // per-head CSR bases
        hipMemsetAsync(cnt_e, 0, N_NODES * sizeof(int), stream);
        count_head_kernel<<<(N_EDGES + 255) / 256, 256, 0, stream>>>(head, cnt_e);
        scanA_kernel<<<SNBLK, SCHUNK, 0, stream>>>(cnt_e, part, N_NODES);
        scanB_kernel<<<1, 1024, 0, stream>>>(part, part, nullptr, SNBLK);
        scanC_kernel<<<SNBLK, SCHUNK, 0, stream>>>(cnt_e, part, base_e, cursor_e, N_NODES);
        if (tier == 1) {
            // two-level bucket sort with coalesced writes
            countCB_kernel<<<NBA, 256, 0, stream>>>(head, cnt_cb);
            scanA_kernel<<<SNB2, SCHUNK, 0, stream>>>(cnt_cb, part, NCB);
            scanB_kernel<<<1, 1024, 0, stream>>>(part, part, nullptr, SNB2);
            scanC_kernel<<<SNB2, SCHUNK, 0, stream>>>(cnt_cb, part, cbase, ccur, NCB);
            binC_kernel<<<NBA, 256, 0, stream>>>(head, cbase, hb);
            sortD_kernel<<<NBUK, 256, 0, stream>>>(cbase, base_e, hb, tail, pf,
                                                   tail_s, pf_s);
            gather2_kernel<1><<<(N_NODES + 3) / 4, 256, 0, stream>>>(
                base_e, cnt_e, tail_s, pf_s, nullptr, tail, pf, hs, agg);
        } else {
            escatterE_kernel<<<(N_EDGES + 255) / 256, 256, 0, stream>>>(
                head, cursor_e, (int*)hb);
            gather2_kernel<0><<<(N_NODES + 3) / 4, 256, 0, stream>>>(
                base_e, cnt_e, nullptr, nullptr, (int*)hb, tail, pf, hs, agg);
        }
    } else {
        hipMemsetAsync(agg, 0, (size_t)N_NODES * 128 * sizeof(float), stream);
        edge_kernel<<<(int)(((long long)N_EDGES * 128) / 256), 256, 0, stream>>>(
            head, tail, pf, hs, agg);
    }

    // ---- BN2 + layer2 (in place on agg) ----
    bucket_jet_kernel<128><<<1024, 256, 0, stream>>>(agg, w, order, baseI, cntI, jet2);
    stats_kernel<128><<<128, 256, 0, stream>>>(jet2, g2, b2, sc2, sh2);
    fused2_kernel<<<(N_NODES + TILE2 - 1) / TILE2, 256, 0, stream>>>(
        agg, sc2, sh2, W2, agg, nullptr);

    // ---- BN3 + layer3 + shortcut add ----
    bucket_jet_kernel<128><<<1024, 256, 0, stream>>>(agg, w, order, baseI, cntI, jet3);
    stats_kernel<128><<<128, 256, 0, stream>>>(jet3, g3, b3, sc3, sh3);
    fused2_kernel<<<(N_NODES + TILE2 - 1) / TILE2, 256, 0, stream>>>(
        agg, sc3, sh3, W3, out, out);

    (void)in_sizes; (void)n_in; (void)out_size;
}

// Round 7
// 568.967 us; speedup vs baseline: 1.2775x; 1.1359x over previous
//
#include <hip/hip_runtime.h>

#define N_NODES 100000
#define N_EDGES 1600000
#define NB      1024
#define EPSF    1e-5f

#define SCHUNK 128
#define SNBLK ((N_NODES + SCHUNK - 1) / SCHUNK)   // 782

#define BUK_SH  7
#define NBUK    ((N_NODES + 127) >> 7)            // 782 buckets of 128 heads
#define EPB     16384
#define NBA     ((N_EDGES + EPB - 1) / EPB)       // 98 binning blocks
#define NCB     (NBUK * NBA)                      // 76,636 count-matrix entries
#define SNB2    ((NCB + SCHUNK - 1) / SCHUNK)     // 599

typedef float f32x4  __attribute__((ext_vector_type(4)));
typedef short bf16x8 __attribute__((ext_vector_type(8)));

__device__ __forceinline__ float bf2f(unsigned short u) {
    union { unsigned int i; float f; } v; v.i = ((unsigned int)u) << 16; return v.f;
}
__device__ __forceinline__ unsigned short f2bf(float f) {
    union { float ff; unsigned int i; } v; v.ff = f;
    unsigned int r = v.i + 0x7FFFu + ((v.i >> 16) & 1u);   // RNE
    return (unsigned short)(r >> 16);
}

// -------------- per-channel mean/var(ddof=1) -> scale/shift --------------
template<int C>
__global__ __launch_bounds__(256) void stats_kernel(const float* __restrict__ jet,
                                                    const float* __restrict__ g,
                                                    const float* __restrict__ b,
                                                    float* __restrict__ scale,
                                                    float* __restrict__ shift) {
    int c = blockIdx.x;
    int t = threadIdx.x;
    float s = 0.f, s2 = 0.f;
    for (int r = t; r < NB; r += 256) {
        float v = jet[r * C + c];
        s += v; s2 += v * v;
    }
    __shared__ float ls[256], ls2[256];
    ls[t] = s; ls2[t] = s2;
    __syncthreads();
    for (int ofs = 128; ofs > 0; ofs >>= 1) {
        if (t < ofs) { ls[t] += ls[t + ofs]; ls2[t] += ls2[t + ofs]; }
        __syncthreads();
    }
    if (t == 0) {
        float mean = ls[0] / (float)NB;
        float var  = (ls2[0] - (float)NB * mean * mean) / (float)(NB - 1);
        float sc   = g[c] / sqrtf(var + EPSF);
        scale[c] = sc;
        shift[c] = b[c] - mean * sc;
    }
}

// ---------------- count kernels ------------------------------------------
__global__ __launch_bounds__(256) void count_head_kernel(const int* __restrict__ head,
                                                         int* __restrict__ cnt) {
    int e = blockIdx.x * 256 + threadIdx.x;
    if (e < N_EDGES) atomicAdd(&cnt[head[e]], 1);
}
__global__ __launch_bounds__(256) void countI_kernel(const int* __restrict__ ind,
                                                     int* __restrict__ cntI) {
    int n = blockIdx.x * 256 + threadIdx.x;
    if (n < N_NODES) atomicAdd(&cntI[ind[n]], 1);
}

// ---------------- scans ---------------------------------------------------
__global__ __launch_bounds__(SCHUNK) void scanA_kernel(const int* __restrict__ cnt,
                                                       int* __restrict__ part, int n) {
    __shared__ int ls[SCHUNK];
    int t = threadIdx.x;
    int i = blockIdx.x * SCHUNK + t;
    ls[t] = (i < n) ? cnt[i] : 0;
    __syncthreads();
    for (int ofs = SCHUNK / 2; ofs > 0; ofs >>= 1) {
        if (t < ofs) ls[t] += ls[t + ofs];
        __syncthreads();
    }
    if (t == 0) part[blockIdx.x] = ls[0];
}

// single-block scan (n <= 1024); EXCLUSIVE prefix to out (and out2)
__global__ __launch_bounds__(1024) void scanB_kernel(const int* __restrict__ in,
                                                     int* __restrict__ out,
                                                     int* __restrict__ out2, int n) {
    __shared__ int ls[1024];
    int t = threadIdx.x;
    int v = (t < n) ? in[t] : 0;
    ls[t] = v;
    __syncthreads();
    for (int ofs = 1; ofs < 1024; ofs <<= 1) {
        int u = (t >= ofs) ? ls[t - ofs] : 0;
        __syncthreads();
        ls[t] += u;
        __syncthreads();
    }
    if (t < n) {
        int e = ls[t] - v;
        out[t] = e;
        if (out2) out2[t] = e;
    }
}

__global__ __launch_bounds__(SCHUNK) void scanC_kernel(const int* __restrict__ cnt,
                                                       const int* __restrict__ poff,
                                                       int* __restrict__ base,
                                                       int* __restrict__ cursor, int n) {
    __shared__ int ls[SCHUNK];
    int t = threadIdx.x;
    int i = blockIdx.x * SCHUNK + t;
    int v = (i < n) ? cnt[i] : 0;
    ls[t] = v;
    __syncthreads();
    for (int ofs = 1; ofs < SCHUNK; ofs <<= 1) {
        int u = (t >= ofs) ? ls[t - ofs] : 0;
        __syncthreads();
        ls[t] += u;
        __syncthreads();
    }
    if (i < n) {
        int bse = poff[blockIdx.x] + ls[t] - v;
        base[i] = bse;
        cursor[i] = bse;
    }
}

// ---- Pass A: per-(bucket, block) histogram, bucket-major output ---------
__global__ __launch_bounds__(256) void countCB_kernel(const int* __restrict__ head,
                                                      int* __restrict__ cnt_cb) {
    __shared__ int h[NBUK];
    int tid = threadIdx.x;
    int blk = blockIdx.x;
    for (int i = tid; i < NBUK; i += 256) h[i] = 0;
    __syncthreads();
    int e0 = blk * EPB;
    for (int k = tid; k < EPB; k += 256) {
        int e = e0 + k;
        if (e < N_EDGES) atomicAdd(&h[head[e] >> BUK_SH], 1);
    }
    __syncthreads();
    for (int i = tid; i < NBUK; i += 256) cnt_cb[i * NBA + blk] = h[i];
}

// ---- Pass C: bin packed records (eid | head_low<<21) into bucket chunks --
__global__ __launch_bounds__(256) void binC_kernel(const int* __restrict__ head,
                                                   const int* __restrict__ cbase,
                                                   unsigned* __restrict__ hb) {
    __shared__ int cur[NBUK];
    int tid = threadIdx.x;
    int blk = blockIdx.x;
    for (int i = tid; i < NBUK; i += 256) cur[i] = cbase[i * NBA + blk];
    __syncthreads();
    int e0 = blk * EPB;
    for (int k = tid; k < EPB; k += 256) {
        int e = e0 + k;
        if (e < N_EDGES) {
            int hd = head[e];
            int b = hd >> BUK_SH;
            int slot = atomicAdd(&cur[b], 1);
            hb[slot] = (unsigned)e | ((unsigned)(hd & 127) << 21);
        }
    }
}

// ---- Pass D: within-bucket CSR placement; random READS, clean writes ----
__global__ __launch_bounds__(256) void sortD_kernel(const int* __restrict__ cbase,
                                                    const int* __restrict__ base_e,
                                                    const unsigned* __restrict__ hb,
                                                    const int* __restrict__ tail,
                                                    const float* __restrict__ pf,
                                                    int* __restrict__ tail_s,
                                                    float* __restrict__ pf_s) {
    __shared__ int hcur[128];
    int tid = threadIdx.x;
    int b = blockIdx.x;
    int h0 = b << BUK_SH;
    if (tid < 128) {
        int h = h0 + tid;
        hcur[tid] = (h < N_NODES) ? base_e[h] : 0;
    }
    __syncthreads();
    int lo = cbase[b * NBA];
    int hi = (b + 1 < NBUK) ? cbase[(b + 1) * NBA] : N_EDGES;
    for (int k = lo + tid; k < hi; k += 256) {
        unsigned rec = hb[k];
        int e = (int)(rec & 0x1FFFFFu);
        int h7 = (int)(rec >> 21);
        int slot = atomicAdd(&hcur[h7], 1);
        tail_s[slot] = tail[e];
        ((float4*)pf_s)[slot] = ((const float4*)pf)[e];
    }
}

// ---------------- legacy scatter (tier-2 fallback) -----------------------
__global__ __launch_bounds__(256) void escatterE_kernel(const int* __restrict__ head,
                                                        int* __restrict__ cursor,
                                                        int* __restrict__ eid) {
    int e = blockIdx.x * 256 + threadIdx.x;
    if (e >= N_EDGES) return;
    int slot = atomicAdd(&cursor[head[e]], 1);
    eid[slot] = e;
}

__global__ __launch_bounds__(256) void scatterI_kernel(const int* __restrict__ ind,
                                                       int* __restrict__ cursorI,
                                                       int* __restrict__ order) {
    int n = blockIdx.x * 256 + threadIdx.x;
    if (n < N_NODES) {
        int pos = atomicAdd(&cursorI[ind[n]], 1);
        order[pos] = n;
    }
}

// ---------- bucket jet: jet[b,c] = sum_{n in bucket b} x[n,c]*w[n] -------
template<int C>
__global__ __launch_bounds__(256) void bucket_jet_kernel(const float* __restrict__ xx,
                                                         const float* __restrict__ w,
                                                         const int* __restrict__ order,
                                                         const int* __restrict__ baseI,
                                                         const int* __restrict__ cntI,
                                                         float* __restrict__ jet) {
    constexpr int G = 256 / C;
    __shared__ float red[256];
    int b = blockIdx.x;
    int g = threadIdx.x / C;
    int c = threadIdx.x % C;
    int s0 = baseI[b], m = cntI[b];
    float s = 0.f;
    for (int k = g; k < m; k += G) {
        int n = order[s0 + k];
        s += xx[(size_t)n * C + c] * w[n];
    }
    red[threadIdx.x] = s;
    __syncthreads();
    for (int half = G / 2; half > 0; half >>= 1) {
        if (g < half) red[g * C + c] += red[(g + half) * C + c];
        __syncthreads();
    }
    if (g == 0) jet[b * C + c] = red[c];
}

// --------- fused1: shortcut GEMM + bn1+relu + @W1^T * w  -----------------
#define TILE1 32
__global__ __launch_bounds__(256) void fused1_kernel(const float* __restrict__ x,
                                                     const float* __restrict__ w,
                                                     const float* __restrict__ scale,
                                                     const float* __restrict__ shift,
                                                     const float* __restrict__ Wsc,
                                                     const float* __restrict__ W1,
                                                     unsigned short* __restrict__ hs,
                                                     float* __restrict__ out) {
    __shared__ __align__(16) float xs[TILE1][68];
    __shared__ __align__(16) float xn[TILE1][68];
    __shared__ __align__(16) float Wl[160][68];
    int tid = threadIdx.x;
    int n0  = blockIdx.x * TILE1;

    for (int i = tid; i < 128 * 64; i += 256) Wl[i >> 6][i & 63] = Wsc[i];
    for (int i = tid; i < 32 * 64;  i += 256) Wl[128 + (i >> 6)][i & 63] = W1[i];
    for (int i = tid; i < TILE1 * 64; i += 256) {
        int r = i >> 6, c = i & 63;
        int n = n0 + r;
        float v = (n < N_NODES) ? x[(size_t)n * 64 + c] : 0.f;
        xs[r][c] = v;
        float vn = v * scale[c] + shift[c];
        xn[r][c] = vn > 0.f ? vn : 0.f;
    }
    __syncthreads();

    int r0 = tid >> 4;
    int s  = tid & 15;
    float acc[2][10];
#pragma unroll
    for (int q = 0; q < 2; q++)
#pragma unroll
        for (int k = 0; k < 10; k++) acc[q][k] = 0.f;

    for (int c = 0; c < 64; c += 4) {
        float4 xr0 = *(const float4*)&xs[r0][c];
        float4 xr1 = *(const float4*)&xs[r0 + 16][c];
        float4 xn0 = *(const float4*)&xn[r0][c];
        float4 xn1 = *(const float4*)&xn[r0 + 16][c];
#pragma unroll
        for (int k = 0; k < 10; k++) {
            int row = (k < 8) ? (s + 16 * k) : (128 + s + 16 * (k - 8));
            float4 wv = *(const float4*)&Wl[row][c];
            float4 a0 = (k < 8) ? xr0 : xn0;
            float4 a1 = (k < 8) ? xr1 : xn1;
            acc[0][k] += a0.x * wv.x + a0.y * wv.y + a0.z * wv.z + a0.w * wv.w;
            acc[1][k] += a1.x * wv.x + a1.y * wv.y + a1.z * wv.z + a1.w * wv.w;
        }
    }
#pragma unroll
    for (int q = 0; q < 2; q++) {
        int n = n0 + r0 + 16 * q;
        if (n < N_NODES) {
            float ww = w[n];
#pragma unroll
            for (int k = 0; k < 8; k++) out[(size_t)n * 128 + s + 16 * k] = acc[q][k];
            hs[n * 32 + s]      = f2bf(acc[q][8] * ww);
            hs[n * 32 + s + 16] = f2bf(acc[q][9] * ww);
        }
    }
}

// ---------- gather: one wave per node, lane = channel pair ---------------
template<int PRE>
__global__ __launch_bounds__(256) void gather2_kernel(const int* __restrict__ base,
                                                      const int* __restrict__ cnt,
                                                      const int* __restrict__ tail_s,
                                                      const float* __restrict__ pf_s,
                                                      const int* __restrict__ eid,
                                                      const int* __restrict__ tail,
                                                      const float* __restrict__ pf,
                                                      const unsigned short* __restrict__ hs,
                                                      float* __restrict__ agg) {
    int n = blockIdx.x * 4 + (threadIdx.x >> 6);
    if (n >= N_NODES) return;
    int lane = threadIdx.x & 63;
    int i = lane >> 1;
    int th = (lane & 1) * 2;
    int s0 = base[n], c = cnt[n];
    float a0 = 0.f, a1 = 0.f;
    int k = 0;
    for (; k + 4 <= c; k += 4) {
        int t0, t1, t2, t3;
        float2 p0, p1, p2, p3;
        if (PRE) {
            t0 = tail_s[s0 + k];     t1 = tail_s[s0 + k + 1];
            t2 = tail_s[s0 + k + 2]; t3 = tail_s[s0 + k + 3];
            p0 = *(const float2*)&pf_s[(size_t)(s0 + k) * 4 + th];
            p1 = *(const float2*)&pf_s[(size_t)(s0 + k + 1) * 4 + th];
            p2 = *(const float2*)&pf_s[(size_t)(s0 + k + 2) * 4 + th];
            p3 = *(const float2*)&pf_s[(size_t)(s0 + k + 3) * 4 + th];
        } else {
            int e0 = eid[s0 + k],     e1 = eid[s0 + k + 1];
            int e2 = eid[s0 + k + 2], e3 = eid[s0 + k + 3];
            t0 = tail[e0]; t1 = tail[e1]; t2 = tail[e2]; t3 = tail[e3];
            p0 = *(const float2*)&pf[(size_t)e0 * 4 + th];
            p1 = *(const float2*)&pf[(size_t)e1 * 4 + th];
            p2 = *(const float2*)&pf[(size_t)e2 * 4 + th];
            p3 = *(const float2*)&pf[(size_t)e3 * 4 + th];
        }
        float h0 = bf2f(hs[(size_t)t0 * 32 + i]);
        float h1 = bf2f(hs[(size_t)t1 * 32 + i]);
        float h2 = bf2f(hs[(size_t)t2 * 32 + i]);
        float h3 = bf2f(hs[(size_t)t3 * 32 + i]);
        a0 += h0 * p0.x; a1 += h0 * p0.y;
        a0 += h1 * p1.x; a1 += h1 * p1.y;
        a0 += h2 * p2.x; a1 += h2 * p2.y;
        a0 += h3 * p3.x; a1 += h3 * p3.y;
    }
    for (; k < c; k++) {
        int t0; float2 p0;
        if (PRE) {
            t0 = tail_s[s0 + k];
            p0 = *(const float2*)&pf_s[(size_t)(s0 + k) * 4 + th];
        } else {
            int e0 = eid[s0 + k];
            t0 = tail[e0];
            p0 = *(const float2*)&pf[(size_t)e0 * 4 + th];
        }
        float h0 = bf2f(hs[(size_t)t0 * 32 + i]);
        a0 += h0 * p0.x; a1 += h0 * p0.y;
    }
    *(float2*)&agg[(size_t)n * 128 + lane * 2] = make_float2(a0, a1);
}

// -------- legacy atomic edge scatter (ultimate fallback) -----------------
__global__ __launch_bounds__(256) void edge_kernel(const int* __restrict__ head,
                                                   const int* __restrict__ tail,
                                                   const float* __restrict__ pf,
                                                   const unsigned short* __restrict__ hs,
                                                   float* __restrict__ agg) {
    long long tid = (long long)blockIdx.x * 256 + threadIdx.x;
    if (tid >= (long long)N_EDGES * 128) return;
    int e = (int)(tid >> 7);
    int j = (int)(tid & 127);
    int i = j >> 2, t = j & 3;
    float v = bf2f(hs[(size_t)tail[e] * 32 + i]) * pf[(size_t)e * 4 + t];
    atomicAdd(&agg[(size_t)head[e] * 128 + j], v);
}

// ------- fused2 MFMA: y = relu(bn(x)) @ W^T (+resid), bf16 inputs --------
// 64-row tile, 4 waves x 16-row strips, 48KB LDS (both xn & full W bf16)
#define TILE2 64
__global__ __launch_bounds__(256) void fused2_kernel(const float* __restrict__ xin,
                                                     const float* __restrict__ scale,
                                                     const float* __restrict__ shift,
                                                     const float* __restrict__ W,
                                                     float* __restrict__ yout,
                                                     const float* __restrict__ resid) {
    // bf16 LDS, byte-swizzled: byte ^= (row&7)<<4
    __shared__ __align__(16) unsigned short xnb[TILE2 * 128];   // 16KB
    __shared__ __align__(16) unsigned short wb[128 * 128];      // 32KB
    int tid = threadIdx.x;
    int n0  = blockIdx.x * TILE2;
    char* xbase = (char*)xnb;
    char* wbase = (char*)wb;

    // stage x: bn+relu -> bf16, 8 elems per chunk, 4 chunks/thread
    for (int idx = tid; idx < TILE2 * 16; idx += 256) {
        int r = idx >> 4;
        int c0 = (idx & 15) << 3;
        int n = n0 + r;
        float4 vA = make_float4(0.f, 0.f, 0.f, 0.f), vB = vA;
        if (n < N_NODES) {
            vA = *(const float4*)&xin[(size_t)n * 128 + c0];
            vB = *(const float4*)&xin[(size_t)n * 128 + c0 + 4];
        }
        float4 scA = *(const float4*)&scale[c0], scB = *(const float4*)&scale[c0 + 4];
        float4 shA = *(const float4*)&shift[c0], shB = *(const float4*)&shift[c0 + 4];
        ushort ua[8];
        ua[0] = f2bf(fmaxf(fmaf(vA.x, scA.x, shA.x), 0.f));
        ua[1] = f2bf(fmaxf(fmaf(vA.y, scA.y, shA.y), 0.f));
        ua[2] = f2bf(fmaxf(fmaf(vA.z, scA.z, shA.z), 0.f));
        ua[3] = f2bf(fmaxf(fmaf(vA.w, scA.w, shA.w), 0.f));
        ua[4] = f2bf(fmaxf(fmaf(vB.x, scB.x, shB.x), 0.f));
        ua[5] = f2bf(fmaxf(fmaf(vB.y, scB.y, shB.y), 0.f));
        ua[6] = f2bf(fmaxf(fmaf(vB.z, scB.z, shB.z), 0.f));
        ua[7] = f2bf(fmaxf(fmaf(vB.w, scB.w, shB.w), 0.f));
        int byte = (r << 8) + ((idx & 15) << 4);
        byte ^= (r & 7) << 4;
        *(bf16x8*)(xbase + byte) = *(bf16x8*)ua;
    }
    // stage W -> bf16 (128x128)
    for (int idx = tid; idx < 128 * 16; idx += 256) {
        int r = idx >> 4;
        int c0 = (idx & 15) << 3;
        float4 vA = *(const float4*)&W[(size_t)r * 128 + c0];
        float4 vB = *(const float4*)&W[(size_t)r * 128 + c0 + 4];
        ushort ua[8];
        ua[0] = f2bf(vA.x); ua[1] = f2bf(vA.y); ua[2] = f2bf(vA.z); ua[3] = f2bf(vA.w);
        ua[4] = f2bf(vB.x); ua[5] = f2bf(vB.y); ua[6] = f2bf(vB.z); ua[7] = f2bf(vB.w);
        int byte = (r << 8) + ((idx & 15) << 4);
        byte ^= (r & 7) << 4;
        *(bf16x8*)(wbase + byte) = *(bf16x8*)ua;
    }
    __syncthreads();

    int wv   = tid >> 6;          // wave 0..3 -> rows [16wv,16wv+16)
    int lane = tid & 63;
    int l15  = lane & 15;
    int lhi  = lane >> 4;         // 0..3
    int swz  = (l15 & 7) << 4;

    f32x4 acc[8];
#pragma unroll
    for (int cf = 0; cf < 8; cf++) acc[cf] = (f32x4){0.f, 0.f, 0.f, 0.f};

#pragma unroll
    for (int ks = 0; ks < 4; ks++) {
        int rA = (wv << 4) + l15;
        int byteA = ((rA << 8) + (ks << 6) + (lhi << 4)) ^ swz;
        bf16x8 a = *(const bf16x8*)(xbase + byteA);
#pragma unroll
        for (int cf = 0; cf < 8; cf++) {
            int rB = (cf << 4) + l15;
            int byteB = ((rB << 8) + (ks << 6) + (lhi << 4)) ^ swz;
            bf16x8 b = *(const bf16x8*)(wbase + byteB);
            acc[cf] = __builtin_amdgcn_mfma_f32_16x16x32_bf16(a, b, acc[cf], 0, 0, 0);
        }
    }

    // epilogue: D row = 16*wv + lhi*4 + j, col = cf*16 + l15
#pragma unroll
    for (int cf = 0; cf < 8; cf++) {
        int col = (cf << 4) + l15;
#pragma unroll
        for (int j = 0; j < 4; j++) {
            int n = n0 + (wv << 4) + (lhi << 2) + j;
            if (n < N_NODES) {
                float v = acc[cf][j];
                if (resid) v += resid[(size_t)n * 128 + col];
                yout[(size_t)n * 128 + col] = v;
            }
        }
    }
}

extern "C" void kernel_launch(void* const* d_in, const int* in_sizes, int n_in,
                              void* d_out, int out_size, void* d_ws, size_t ws_size,
                              hipStream_t stream) {
    const float* x    = (const float*)d_in[0];
    const float* w    = (const float*)d_in[1];
    const float* pf   = (const float*)d_in[2];
    const int*   head = (const int*)d_in[3];
    const int*   tail = (const int*)d_in[4];
    const int*   ind  = (const int*)d_in[5];
    const float* Wsc  = (const float*)d_in[6];
    const float* g1   = (const float*)d_in[7];
    const float* b1   = (const float*)d_in[8];
    const float* W1   = (const float*)d_in[9];
    const float* g2   = (const float*)d_in[10];
    const float* b2   = (const float*)d_in[11];
    const float* W2   = (const float*)d_in[12];
    const float* g3   = (const float*)d_in[13];
    const float* b3   = (const float*)d_in[14];
    const float* W3   = (const float*)d_in[15];
    float* out = (float*)d_out;

    char* p = (char*)d_ws;
    unsigned short* hs = (unsigned short*)p;  p += (size_t)N_NODES * 32 * 2;   // 6.4MB
    float* agg  = (float*)p;                  p += (size_t)N_NODES * 128 * 4;  // 51.2MB
    float* jet1 = (float*)p;                  p += 1024 * 64 * 4;
    float* jet2 = (float*)p;                  p += 1024 * 128 * 4;
    float* jet3 = (float*)p;                  p += 1024 * 128 * 4;
    float* sc1 = (float*)p; p += 64 * 4;  float* sh1 = (float*)p; p += 64 * 4;
    float* sc2 = (float*)p; p += 128 * 4; float* sh2 = (float*)p; p += 128 * 4;
    float* sc3 = (float*)p; p += 128 * 4; float* sh3 = (float*)p; p += 128 * 4;
    int* cnt_e    = (int*)p; p += (size_t)N_NODES * 4;
    int* base_e   = (int*)p; p += (size_t)N_NODES * 4;
    int* cursor_e = (int*)p; p += (size_t)N_NODES * 4;
    int* part     = (int*)p; p += 1024 * 4;
    int* cntI     = (int*)p; p += 1024 * 4;
    int* baseI    = (int*)p; p += 1024 * 4;
    int* cursorI  = (int*)p; p += 1024 * 4;
    int* order    = (int*)p; p += (size_t)N_NODES * 4;
    unsigned* hb  = (unsigned*)p; p += (size_t)N_EDGES * 4;   // 6.4MB (tier2: eid)
    size_t need_t2 = (size_t)(p - (char*)d_ws);
    int* cnt_cb   = (int*)p; p += (size_t)NCB * 4;            // 307KB
    int* cbase    = (int*)p; p += (size_t)NCB * 4;
    int* ccur     = (int*)p; p += (size_t)NCB * 4;
    int*   tail_s = (int*)p;   p += (size_t)N_EDGES * 4;      // 6.4MB
    float* pf_s   = (float*)p; p += (size_t)N_EDGES * 16;     // 25.6MB
    size_t need_t1 = (size_t)(p - (char*)d_ws);
    int tier = (ws_size >= need_t1) ? 1 : (ws_size >= need_t2) ? 2 : 3;

    // ---- indicator-CSR (atomic-free jets) ----
    hipMemsetAsync(cntI, 0, 1024 * sizeof(int), stream);
    countI_kernel<<<(N_NODES + 255) / 256, 256, 0, stream>>>(ind, cntI);
    scanB_kernel<<<1, 1024, 0, stream>>>(cntI, baseI, cursorI, 1024);
    scatterI_kernel<<<(N_NODES + 255) / 256, 256, 0, stream>>>(ind, cursorI, order);

    // ---- BN1 stats ----
    bucket_jet_kernel<64><<<1024, 256, 0, stream>>>(x, w, order, baseI, cntI, jet1);
    stats_kernel<64><<<64, 256, 0, stream>>>(jet1, g1, b1, sc1, sh1);

    // ---- shortcut + layer1 ----
    fused1_kernel<<<(N_NODES + TILE1 - 1) / TILE1, 256, 0, stream>>>(
        x, w, sc1, sh1, Wsc, W1, hs, out);

    // ---- edge message passing ----
    if (tier <= 2) {
        // per-head CSR bases
        hipMemsetAsync(cnt_e, 0, N_NODES * sizeof(int), stream);
        count_head_kernel<<<(N_EDGES + 255) / 256, 256, 0, stream>>>(head, cnt_e);
        scanA_kernel<<<SNBLK, SCHUNK, 0, stream>>>(cnt_e, part, N_NODES);
        scanB_kernel<<<1, 1024, 0, stream>>>(part, part, nullptr, SNBLK);
        scanC_kernel<<<SNBLK, SCHUNK, 0, stream>>>(cnt_e, part, base_e, cursor_e, N_NODES);
        if (tier == 1) {
            // two-level bucket sort with coalesced writes
            countCB_kernel<<<NBA, 256, 0, stream>>>(head, cnt_cb);
            scanA_kernel<<<SNB2, SCHUNK, 0, stream>>>(cnt_cb, part, NCB);
            scanB_kernel<<<1, 1024, 0, stream>>>(part, part, nullptr, SNB2);
            scanC_kernel<<<SNB2, SCHUNK, 0, stream>>>(cnt_cb, part, cbase, ccur, NCB);
            binC_kernel<<<NBA, 256, 0, stream>>>(head, cbase, hb);
            sortD_kernel<<<NBUK, 256, 0, stream>>>(cbase, base_e, hb, tail, pf,
                                                   tail_s, pf_s);
            gather2_kernel<1><<<(N_NODES + 3) / 4, 256, 0, stream>>>(
                base_e, cnt_e, tail_s, pf_s, nullptr, tail, pf, hs, agg);
        } else {
            escatterE_kernel<<<(N_EDGES + 255) / 256, 256, 0, stream>>>(
                head, cursor_e, (int*)hb);
            gather2_kernel<0><<<(N_NODES + 3) / 4, 256, 0, stream>>>(
                base_e, cnt_e, nullptr, nullptr, (int*)hb, tail, pf, hs, agg);
        }
    } else {
        hipMemsetAsync(agg, 0, (size_t)N_NODES * 128 * sizeof(float), stream);
        edge_kernel<<<(int)(((long long)N_EDGES * 128) / 256), 256, 0, stream>>>(
            head, tail, pf, hs, agg);
    }

    // ---- BN2 + layer2 (in place on agg) ----
    bucket_jet_kernel<128><<<1024, 256, 0, stream>>>(agg, w, order, baseI, cntI, jet2);
    stats_kernel<128><<<128, 256, 0, stream>>>(jet2, g2, b2, sc2, sh2);
    fused2_kernel<<<(N_NODES + TILE2 - 1) / TILE2, 256, 0, stream>>>(
        agg, sc2, sh2, W2, agg, nullptr);

    // ---- BN3 + layer3 + shortcut add ----
    bucket_jet_kernel<128><<<1024, 256, 0, stream>>>(agg, w, order, baseI, cntI, jet3);
    stats_kernel<128><<<128, 256, 0, stream>>>(jet3, g3, b3, sc3, sh3);
    fused2_kernel<<<(N_NODES + TILE2 - 1) / TILE2, 256, 0, stream>>>(
        agg, sc3, sh3, W3, out, out);

    (void)in_sizes; (void)n_in; (void)out_size;
}

// Round 8
// 468.664 us; speedup vs baseline: 1.5510x; 1.2140x over previous
//
#include <hip/hip_runtime.h>

#define N_NODES 100000
#define N_EDGES 1600000
#define NB      1024
#define EPSF    1e-5f

#define SCHUNK 128
#define SNBLK ((N_NODES + SCHUNK - 1) / SCHUNK)   // 782

#define BUK_SH  7
#define NBUK    ((N_NODES + 127) >> 7)            // 782 buckets of 128 heads
#define EPB     16384
#define NBA     ((N_EDGES + EPB - 1) / EPB)       // 98 binning blocks
#define NCB     (NBUK * NBA)                      // 76,636 count-matrix entries
#define SNB2    ((NCB + SCHUNK - 1) / SCHUNK)     // 599

typedef float f32x4  __attribute__((ext_vector_type(4)));
typedef short bf16x8 __attribute__((ext_vector_type(8)));

__device__ __forceinline__ float bf2f(unsigned short u) {
    union { unsigned int i; float f; } v; v.i = ((unsigned int)u) << 16; return v.f;
}
__device__ __forceinline__ unsigned short f2bf(float f) {
    union { float ff; unsigned int i; } v; v.ff = f;
    unsigned int r = v.i + 0x7FFFu + ((v.i >> 16) & 1u);   // RNE
    return (unsigned short)(r >> 16);
}

// -------------- per-channel mean/var(ddof=1) -> scale/shift --------------
template<int C>
__global__ __launch_bounds__(256) void stats_kernel(const float* __restrict__ jet,
                                                    const float* __restrict__ g,
                                                    const float* __restrict__ b,
                                                    float* __restrict__ scale,
                                                    float* __restrict__ shift) {
    int c = blockIdx.x;
    int t = threadIdx.x;
    float s = 0.f, s2 = 0.f;
    for (int r = t; r < NB; r += 256) {
        float v = jet[r * C + c];
        s += v; s2 += v * v;
    }
    __shared__ float ls[256], ls2[256];
    ls[t] = s; ls2[t] = s2;
    __syncthreads();
    for (int ofs = 128; ofs > 0; ofs >>= 1) {
        if (t < ofs) { ls[t] += ls[t + ofs]; ls2[t] += ls2[t + ofs]; }
        __syncthreads();
    }
    if (t == 0) {
        float mean = ls[0] / (float)NB;
        float var  = (ls2[0] - (float)NB * mean * mean) / (float)(NB - 1);
        float sc   = g[c] / sqrtf(var + EPSF);
        scale[c] = sc;
        shift[c] = b[c] - mean * sc;
    }
}

// ---------------- count kernels ------------------------------------------
__global__ __launch_bounds__(256) void countI_kernel(const int* __restrict__ ind,
                                                     int* __restrict__ cntI) {
    int n = blockIdx.x * 256 + threadIdx.x;
    if (n < N_NODES) atomicAdd(&cntI[ind[n]], 1);
}

// merged: per-head counts (global atomics) + per-(bucket,block) histogram
__global__ __launch_bounds__(256) void countBoth_kernel(const int* __restrict__ head,
                                                        int* __restrict__ cnt_e,
                                                        int* __restrict__ cnt_cb) {
    __shared__ int h[NBUK];
    int tid = threadIdx.x;
    int blk = blockIdx.x;
    for (int i = tid; i < NBUK; i += 256) h[i] = 0;
    __syncthreads();
    int e0 = blk * EPB;
    for (int k = tid; k < EPB; k += 256) {
        int e = e0 + k;
        if (e < N_EDGES) {
            int hd = head[e];
            atomicAdd(&cnt_e[hd], 1);
            atomicAdd(&h[hd >> BUK_SH], 1);
        }
    }
    __syncthreads();
    for (int i = tid; i < NBUK; i += 256) cnt_cb[i * NBA + blk] = h[i];
}

// ---------------- scans ---------------------------------------------------
__global__ __launch_bounds__(SCHUNK) void scanA_kernel(const int* __restrict__ cnt,
                                                       int* __restrict__ part, int n) {
    __shared__ int ls[SCHUNK];
    int t = threadIdx.x;
    int i = blockIdx.x * SCHUNK + t;
    ls[t] = (i < n) ? cnt[i] : 0;
    __syncthreads();
    for (int ofs = SCHUNK / 2; ofs > 0; ofs >>= 1) {
        if (t < ofs) ls[t] += ls[t + ofs];
        __syncthreads();
    }
    if (t == 0) part[blockIdx.x] = ls[0];
}

// single-block scan (n <= 1024); EXCLUSIVE prefix to out (and out2)
__global__ __launch_bounds__(1024) void scanB_kernel(const int* __restrict__ in,
                                                     int* __restrict__ out,
                                                     int* __restrict__ out2, int n) {
    __shared__ int ls[1024];
    int t = threadIdx.x;
    int v = (t < n) ? in[t] : 0;
    ls[t] = v;
    __syncthreads();
    for (int ofs = 1; ofs < 1024; ofs <<= 1) {
        int u = (t >= ofs) ? ls[t - ofs] : 0;
        __syncthreads();
        ls[t] += u;
        __syncthreads();
    }
    if (t < n) {
        int e = ls[t] - v;
        out[t] = e;
        if (out2) out2[t] = e;
    }
}

__global__ __launch_bounds__(SCHUNK) void scanC_kernel(const int* __restrict__ cnt,
                                                       const int* __restrict__ poff,
                                                       int* __restrict__ base,
                                                       int* __restrict__ cursor, int n) {
    __shared__ int ls[SCHUNK];
    int t = threadIdx.x;
    int i = blockIdx.x * SCHUNK + t;
    int v = (i < n) ? cnt[i] : 0;
    ls[t] = v;
    __syncthreads();
    for (int ofs = 1; ofs < SCHUNK; ofs <<= 1) {
        int u = (t >= ofs) ? ls[t - ofs] : 0;
        __syncthreads();
        ls[t] += u;
        __syncthreads();
    }
    if (i < n) {
        int bse = poff[blockIdx.x] + ls[t] - v;
        base[i] = bse;
        cursor[i] = bse;
    }
}

// ---- Pass C: bin packed records (eid | head_low<<21) into bucket chunks --
__global__ __launch_bounds__(256) void binC_kernel(const int* __restrict__ head,
                                                   const int* __restrict__ cbase,
                                                   unsigned* __restrict__ hb) {
    __shared__ int cur[NBUK];
    int tid = threadIdx.x;
    int blk = blockIdx.x;
    for (int i = tid; i < NBUK; i += 256) cur[i] = cbase[i * NBA + blk];
    __syncthreads();
    int e0 = blk * EPB;
    for (int k = tid; k < EPB; k += 256) {
        int e = e0 + k;
        if (e < N_EDGES) {
            int hd = head[e];
            int b = hd >> BUK_SH;
            int slot = atomicAdd(&cur[b], 1);
            hb[slot] = (unsigned)e | ((unsigned)(hd & 127) << 21);
        }
    }
}

// ---- Pass D: within-bucket CSR placement; random READS, clean writes ----
__global__ __launch_bounds__(256) void sortD_kernel(const int* __restrict__ cbase,
                                                    const int* __restrict__ base_e,
                                                    const unsigned* __restrict__ hb,
                                                    const int* __restrict__ tail,
                                                    const float* __restrict__ pf,
                                                    int* __restrict__ tail_s,
                                                    float* __restrict__ pf_s) {
    __shared__ int hcur[128];
    int tid = threadIdx.x;
    int b = blockIdx.x;
    int h0 = b << BUK_SH;
    if (tid < 128) {
        int h = h0 + tid;
        hcur[tid] = (h < N_NODES) ? base_e[h] : 0;
    }
    __syncthreads();
    int lo = cbase[b * NBA];
    int hi = (b + 1 < NBUK) ? cbase[(b + 1) * NBA] : N_EDGES;
    for (int k = lo + tid; k < hi; k += 256) {
        unsigned rec = hb[k];
        int e = (int)(rec & 0x1FFFFFu);
        int h7 = (int)(rec >> 21);
        int slot = atomicAdd(&hcur[h7], 1);
        tail_s[slot] = tail[e];
        ((float4*)pf_s)[slot] = ((const float4*)pf)[e];
    }
}

// ---------------- legacy scatter (tier-2 fallback) -----------------------
__global__ __launch_bounds__(256) void escatterE_kernel(const int* __restrict__ head,
                                                        int* __restrict__ cursor,
                                                        int* __restrict__ eid) {
    int e = blockIdx.x * 256 + threadIdx.x;
    if (e >= N_EDGES) return;
    int slot = atomicAdd(&cursor[head[e]], 1);
    eid[slot] = e;
}

__global__ __launch_bounds__(256) void scatterI_kernel(const int* __restrict__ ind,
                                                       int* __restrict__ cursorI,
                                                       int* __restrict__ order) {
    int n = blockIdx.x * 256 + threadIdx.x;
    if (n < N_NODES) {
        int pos = atomicAdd(&cursorI[ind[n]], 1);
        order[pos] = n;
    }
}

// ---------- bucket jet (f32 input): jet[b,c] = sum x[n,c]*w[n] -----------
template<int C>
__global__ __launch_bounds__(256) void bucket_jet_kernel(const float* __restrict__ xx,
                                                         const float* __restrict__ w,
                                                         const int* __restrict__ order,
                                                         const int* __restrict__ baseI,
                                                         const int* __restrict__ cntI,
                                                         float* __restrict__ jet) {
    constexpr int G = 256 / C;
    __shared__ float red[256];
    int b = blockIdx.x;
    int g = threadIdx.x / C;
    int c = threadIdx.x % C;
    int s0 = baseI[b], m = cntI[b];
    float s = 0.f;
    for (int k = g; k < m; k += G) {
        int n = order[s0 + k];
        s += xx[(size_t)n * C + c] * w[n];
    }
    red[threadIdx.x] = s;
    __syncthreads();
    for (int half = G / 2; half > 0; half >>= 1) {
        if (g < half) red[g * C + c] += red[(g + half) * C + c];
        __syncthreads();
    }
    if (g == 0) jet[b * C + c] = red[c];
}

// ---------- bucket jet (bf16 input, C=128): uint-packed reads ------------
__global__ __launch_bounds__(256) void bucket_jet_bf128_kernel(const unsigned short* __restrict__ xx,
                                                               const float* __restrict__ w,
                                                               const int* __restrict__ order,
                                                               const int* __restrict__ baseI,
                                                               const int* __restrict__ cntI,
                                                               float* __restrict__ jet) {
    __shared__ float redA[256], redB[256];
    int b = blockIdx.x;
    int g  = threadIdx.x >> 6;     // 4 groups
    int c2 = threadIdx.x & 63;     // channel pair
    int s0 = baseI[b], m = cntI[b];
    float a0 = 0.f, a1 = 0.f;
    for (int k = g; k < m; k += 4) {
        int n = order[s0 + k];
        float wn = w[n];
        unsigned u = ((const unsigned*)xx)[(size_t)n * 64 + c2];
        a0 += bf2f((unsigned short)(u & 0xFFFFu)) * wn;
        a1 += bf2f((unsigned short)(u >> 16)) * wn;
    }
    redA[threadIdx.x] = a0; redB[threadIdx.x] = a1;
    __syncthreads();
    for (int half = 2; half > 0; half >>= 1) {
        if (g < half) {
            redA[g * 64 + c2] += redA[(g + half) * 64 + c2];
            redB[g * 64 + c2] += redB[(g + half) * 64 + c2];
        }
        __syncthreads();
    }
    if (g == 0) {
        jet[b * 128 + 2 * c2]     = redA[c2];
        jet[b * 128 + 2 * c2 + 1] = redB[c2];
    }
}

// --------- fused1 MFMA: shortcut GEMM + bn1+relu + @W1^T * w -------------
// 64-row tile, K=64; 10 col-frags: 0..7 raw-x @ Wsc, 8..9 norm-x @ W1
#define TILE1 64
__global__ __launch_bounds__(256) void fused1_kernel(const float* __restrict__ x,
                                                     const float* __restrict__ w,
                                                     const float* __restrict__ scale,
                                                     const float* __restrict__ shift,
                                                     const float* __restrict__ Wsc,
                                                     const float* __restrict__ W1,
                                                     unsigned short* __restrict__ hs,
                                                     float* __restrict__ out) {
    __shared__ __align__(16) unsigned short xsb[TILE1 * 64];   // raw, 8KB
    __shared__ __align__(16) unsigned short xnb[TILE1 * 64];   // norm, 8KB
    __shared__ __align__(16) unsigned short wlb[160 * 64];     // 20KB
    int tid = threadIdx.x;
    int n0  = blockIdx.x * TILE1;
    char* xsb_ = (char*)xsb; char* xnb_ = (char*)xnb; char* wlb_ = (char*)wlb;

    for (int idx = tid; idx < TILE1 * 8; idx += 256) {
        int r = idx >> 3, c0 = (idx & 7) << 3;
        int n = n0 + r;
        float4 vA = make_float4(0.f, 0.f, 0.f, 0.f), vB = vA;
        if (n < N_NODES) {
            vA = *(const float4*)&x[(size_t)n * 64 + c0];
            vB = *(const float4*)&x[(size_t)n * 64 + c0 + 4];
        }
        float4 scA = *(const float4*)&scale[c0], scB = *(const float4*)&scale[c0 + 4];
        float4 shA = *(const float4*)&shift[c0], shB = *(const float4*)&shift[c0 + 4];
        unsigned short ra[8], na[8];
        ra[0] = f2bf(vA.x); ra[1] = f2bf(vA.y); ra[2] = f2bf(vA.z); ra[3] = f2bf(vA.w);
        ra[4] = f2bf(vB.x); ra[5] = f2bf(vB.y); ra[6] = f2bf(vB.z); ra[7] = f2bf(vB.w);
        na[0] = f2bf(fmaxf(fmaf(vA.x, scA.x, shA.x), 0.f));
        na[1] = f2bf(fmaxf(fmaf(vA.y, scA.y, shA.y), 0.f));
        na[2] = f2bf(fmaxf(fmaf(vA.z, scA.z, shA.z), 0.f));
        na[3] = f2bf(fmaxf(fmaf(vA.w, scA.w, shA.w), 0.f));
        na[4] = f2bf(fmaxf(fmaf(vB.x, scB.x, shB.x), 0.f));
        na[5] = f2bf(fmaxf(fmaf(vB.y, scB.y, shB.y), 0.f));
        na[6] = f2bf(fmaxf(fmaf(vB.z, scB.z, shB.z), 0.f));
        na[7] = f2bf(fmaxf(fmaf(vB.w, scB.w, shB.w), 0.f));
        int byte = ((r << 7) + ((idx & 7) << 4)) ^ ((r & 7) << 4);
        *(bf16x8*)(xsb_ + byte) = *(bf16x8*)ra;
        *(bf16x8*)(xnb_ + byte) = *(bf16x8*)na;
    }
    for (int idx = tid; idx < 160 * 8; idx += 256) {
        int r = idx >> 3, c0 = (idx & 7) << 3;
        const float* src = (r < 128) ? &Wsc[(size_t)r * 64 + c0]
                                     : &W1[(size_t)(r - 128) * 64 + c0];
        float4 vA = *(const float4*)&src[0];
        float4 vB = *(const float4*)&src[4];
        unsigned short ua[8];
        ua[0] = f2bf(vA.x); ua[1] = f2bf(vA.y); ua[2] = f2bf(vA.z); ua[3] = f2bf(vA.w);
        ua[4] = f2bf(vB.x); ua[5] = f2bf(vB.y); ua[6] = f2bf(vB.z); ua[7] = f2bf(vB.w);
        int byte = ((r << 7) + ((idx & 7) << 4)) ^ ((r & 7) << 4);
        *(bf16x8*)(wlb_ + byte) = *(bf16x8*)ua;
    }
    __syncthreads();

    int wv   = tid >> 6;
    int lane = tid & 63;
    int l15  = lane & 15;
    int lhi  = lane >> 4;

    f32x4 acc[10];
#pragma unroll
    for (int cf = 0; cf < 10; cf++) acc[cf] = (f32x4){0.f, 0.f, 0.f, 0.f};

#pragma unroll
    for (int ks = 0; ks < 2; ks++) {
        int rA = (wv << 4) + l15;
        int byteA = ((rA << 7) + (ks << 6) + (lhi << 4)) ^ ((rA & 7) << 4);
        bf16x8 araw  = *(const bf16x8*)(xsb_ + byteA);
        bf16x8 anorm = *(const bf16x8*)(xnb_ + byteA);
#pragma unroll
        for (int cf = 0; cf < 10; cf++) {
            int rB = (cf << 4) + l15;
            int byteB = ((rB << 7) + (ks << 6) + (lhi << 4)) ^ ((rB & 7) << 4);
            bf16x8 b = *(const bf16x8*)(wlb_ + byteB);
            acc[cf] = __builtin_amdgcn_mfma_f32_16x16x32_bf16(
                (cf < 8) ? araw : anorm, b, acc[cf], 0, 0, 0);
        }
    }

    int nn[4]; float ww[4];
#pragma unroll
    for (int j = 0; j < 4; j++) {
        nn[j] = n0 + (wv << 4) + (lhi << 2) + j;
        ww[j] = (nn[j] < N_NODES) ? w[nn[j]] : 0.f;
    }
#pragma unroll
    for (int cf = 0; cf < 8; cf++) {
        int col = (cf << 4) + l15;
#pragma unroll
        for (int j = 0; j < 4; j++)
            if (nn[j] < N_NODES) out[(size_t)nn[j] * 128 + col] = acc[cf][j];
    }
#pragma unroll
    for (int cf = 8; cf < 10; cf++) {
        int co = ((cf - 8) << 4) + l15;
#pragma unroll
        for (int j = 0; j < 4; j++)
            if (nn[j] < N_NODES) hs[(size_t)nn[j] * 32 + co] = f2bf(acc[cf][j] * ww[j]);
    }
}

// ---------- gather: one wave per node, lane = channel pair; bf16 out -----
template<int PRE>
__global__ __launch_bounds__(256) void gather2_kernel(const int* __restrict__ base,
                                                      const int* __restrict__ cnt,
                                                      const int* __restrict__ tail_s,
                                                      const float* __restrict__ pf_s,
                                                      const int* __restrict__ eid,
                                                      const int* __restrict__ tail,
                                                      const float* __restrict__ pf,
                                                      const unsigned short* __restrict__ hs,
                                                      unsigned short* __restrict__ agg) {
    int n = blockIdx.x * 4 + (threadIdx.x >> 6);
    if (n >= N_NODES) return;
    int lane = threadIdx.x & 63;
    int i = lane >> 1;
    int th = (lane & 1) * 2;
    int s0 = base[n], c = cnt[n];
    float a0 = 0.f, a1 = 0.f;
    int k = 0;
    for (; k + 4 <= c; k += 4) {
        int t0, t1, t2, t3;
        float2 p0, p1, p2, p3;
        if (PRE) {
            t0 = tail_s[s0 + k];     t1 = tail_s[s0 + k + 1];
            t2 = tail_s[s0 + k + 2]; t3 = tail_s[s0 + k + 3];
            p0 = *(const float2*)&pf_s[(size_t)(s0 + k) * 4 + th];
            p1 = *(const float2*)&pf_s[(size_t)(s0 + k + 1) * 4 + th];
            p2 = *(const float2*)&pf_s[(size_t)(s0 + k + 2) * 4 + th];
            p3 = *(const float2*)&pf_s[(size_t)(s0 + k + 3) * 4 + th];
        } else {
            int e0 = eid[s0 + k],     e1 = eid[s0 + k + 1];
            int e2 = eid[s0 + k + 2], e3 = eid[s0 + k + 3];
            t0 = tail[e0]; t1 = tail[e1]; t2 = tail[e2]; t3 = tail[e3];
            p0 = *(const float2*)&pf[(size_t)e0 * 4 + th];
            p1 = *(const float2*)&pf[(size_t)e1 * 4 + th];
            p2 = *(const float2*)&pf[(size_t)e2 * 4 + th];
            p3 = *(const float2*)&pf[(size_t)e3 * 4 + th];
        }
        float h0 = bf2f(hs[(size_t)t0 * 32 + i]);
        float h1 = bf2f(hs[(size_t)t1 * 32 + i]);
        float h2 = bf2f(hs[(size_t)t2 * 32 + i]);
        float h3 = bf2f(hs[(size_t)t3 * 32 + i]);
        a0 += h0 * p0.x; a1 += h0 * p0.y;
        a0 += h1 * p1.x; a1 += h1 * p1.y;
        a0 += h2 * p2.x; a1 += h2 * p2.y;
        a0 += h3 * p3.x; a1 += h3 * p3.y;
    }
    for (; k < c; k++) {
        int t0; float2 p0;
        if (PRE) {
            t0 = tail_s[s0 + k];
            p0 = *(const float2*)&pf_s[(size_t)(s0 + k) * 4 + th];
        } else {
            int e0 = eid[s0 + k];
            t0 = tail[e0];
            p0 = *(const float2*)&pf[(size_t)e0 * 4 + th];
        }
        float h0 = bf2f(hs[(size_t)t0 * 32 + i]);
        a0 += h0 * p0.x; a1 += h0 * p0.y;
    }
    unsigned pk = (unsigned)f2bf(a0) | ((unsigned)f2bf(a1) << 16);
    ((unsigned*)agg)[(size_t)n * 64 + lane] = pk;
}

// -------- legacy atomic edge scatter (tier-3, f32 agg) -------------------
__global__ __launch_bounds__(256) void edge_kernel(const int* __restrict__ head,
                                                   const int* __restrict__ tail,
                                                   const float* __restrict__ pf,
                                                   const unsigned short* __restrict__ hs,
                                                   float* __restrict__ agg) {
    long long tid = (long long)blockIdx.x * 256 + threadIdx.x;
    if (tid >= (long long)N_EDGES * 128) return;
    int e = (int)(tid >> 7);
    int j = (int)(tid & 127);
    int i = j >> 2, t = j & 3;
    float v = bf2f(hs[(size_t)tail[e] * 32 + i]) * pf[(size_t)e * 4 + t];
    atomicAdd(&agg[(size_t)head[e] * 128 + j], v);
}

// ------- fused2 MFMA: y = relu(bn(x)) @ W^T (+resid) ---------------------
// templated on input/output dtype (bf16 or f32); in-place safe per 64-row tile
#define TILE2 64
template<int INBF, int OUTBF>
__global__ __launch_bounds__(256) void fused2_kernel(const void* __restrict__ xin_,
                                                     const float* __restrict__ scale,
                                                     const float* __restrict__ shift,
                                                     const float* __restrict__ W,
                                                     void* __restrict__ yout_,
                                                     const float* __restrict__ resid) {
    __shared__ __align__(16) unsigned short xnb[TILE2 * 128];   // 16KB
    __shared__ __align__(16) unsigned short wb[128 * 128];      // 32KB
    int tid = threadIdx.x;
    int n0  = blockIdx.x * TILE2;
    char* xbase = (char*)xnb;
    char* wbase = (char*)wb;

    for (int idx = tid; idx < TILE2 * 16; idx += 256) {
        int r = idx >> 4;
        int c0 = (idx & 15) << 3;
        int n = n0 + r;
        float f[8];
        if (n < N_NODES) {
            if (INBF) {
                const unsigned short* xu = (const unsigned short*)xin_;
                uint4 U = *(const uint4*)(xu + (size_t)n * 128 + c0);
                f[0] = bf2f((unsigned short)(U.x & 0xFFFFu)); f[1] = bf2f((unsigned short)(U.x >> 16));
                f[2] = bf2f((unsigned short)(U.y & 0xFFFFu)); f[3] = bf2f((unsigned short)(U.y >> 16));
                f[4] = bf2f((unsigned short)(U.z & 0xFFFFu)); f[5] = bf2f((unsigned short)(U.z >> 16));
                f[6] = bf2f((unsigned short)(U.w & 0xFFFFu)); f[7] = bf2f((unsigned short)(U.w >> 16));
            } else {
                const float* xf = (const float*)xin_;
                float4 vA = *(const float4*)&xf[(size_t)n * 128 + c0];
                float4 vB = *(const float4*)&xf[(size_t)n * 128 + c0 + 4];
                f[0] = vA.x; f[1] = vA.y; f[2] = vA.z; f[3] = vA.w;
                f[4] = vB.x; f[5] = vB.y; f[6] = vB.z; f[7] = vB.w;
            }
        } else {
#pragma unroll
            for (int q = 0; q < 8; q++) f[q] = 0.f;
        }
        unsigned short ua[8];
#pragma unroll
        for (int q = 0; q < 8; q++)
            ua[q] = f2bf(fmaxf(fmaf(f[q], scale[c0 + q], shift[c0 + q]), 0.f));
        int byte = ((r << 8) + ((idx & 15) << 4)) ^ ((r & 7) << 4);
        *(bf16x8*)(xbase + byte) = *(bf16x8*)ua;
    }
    for (int idx = tid; idx < 128 * 16; idx += 256) {
        int r = idx >> 4;
        int c0 = (idx & 15) << 3;
        float4 vA = *(const float4*)&W[(size_t)r * 128 + c0];
        float4 vB = *(const float4*)&W[(size_t)r * 128 + c0 + 4];
        unsigned short ua[8];
        ua[0] = f2bf(vA.x); ua[1] = f2bf(vA.y); ua[2] = f2bf(vA.z); ua[3] = f2bf(vA.w);
        ua[4] = f2bf(vB.x); ua[5] = f2bf(vB.y); ua[6] = f2bf(vB.z); ua[7] = f2bf(vB.w);
        int byte = ((r << 8) + ((idx & 15) << 4)) ^ ((r & 7) << 4);
        *(bf16x8*)(wbase + byte) = *(bf16x8*)ua;
    }
    __syncthreads();

    int wv   = tid >> 6;
    int lane = tid & 63;
    int l15  = lane & 15;
    int lhi  = lane >> 4;

    f32x4 acc[8];
#pragma unroll
    for (int cf = 0; cf < 8; cf++) acc[cf] = (f32x4){0.f, 0.f, 0.f, 0.f};

#pragma unroll
    for (int ks = 0; ks < 4; ks++) {
        int rA = (wv << 4) + l15;
        int byteA = ((rA << 8) + (ks << 6) + (lhi << 4)) ^ ((rA & 7) << 4);
        bf16x8 a = *(const bf16x8*)(xbase + byteA);
#pragma unroll
        for (int cf = 0; cf < 8; cf++) {
            int rB = (cf << 4) + l15;
            int byteB = ((rB << 8) + (ks << 6) + (lhi << 4)) ^ ((rB & 7) << 4);
            bf16x8 b = *(const bf16x8*)(wbase + byteB);
            acc[cf] = __builtin_amdgcn_mfma_f32_16x16x32_bf16(a, b, acc[cf], 0, 0, 0);
        }
    }

#pragma unroll
    for (int cf = 0; cf < 8; cf++) {
        int col = (cf << 4) + l15;
#pragma unroll
        for (int j = 0; j < 4; j++) {
            int n = n0 + (wv << 4) + (lhi << 2) + j;
            if (n < N_NODES) {
                float v = acc[cf][j];
                if (resid) v += resid[(size_t)n * 128 + col];
                if (OUTBF) ((unsigned short*)yout_)[(size_t)n * 128 + col] = f2bf(v);
                else       ((float*)yout_)[(size_t)n * 128 + col] = v;
            }
        }
    }
}

extern "C" void kernel_launch(void* const* d_in, const int* in_sizes, int n_in,
                              void* d_out, int out_size, void* d_ws, size_t ws_size,
                              hipStream_t stream) {
    const float* x    = (const float*)d_in[0];
    const float* w    = (const float*)d_in[1];
    const float* pf   = (const float*)d_in[2];
    const int*   head = (const int*)d_in[3];
    const int*   tail = (const int*)d_in[4];
    const int*   ind  = (const int*)d_in[5];
    const float* Wsc  = (const float*)d_in[6];
    const float* g1   = (const float*)d_in[7];
    const float* b1   = (const float*)d_in[8];
    const float* W1   = (const float*)d_in[9];
    const float* g2   = (const float*)d_in[10];
    const float* b2   = (const float*)d_in[11];
    const float* W2   = (const float*)d_in[12];
    const float* g3   = (const float*)d_in[13];
    const float* b3   = (const float*)d_in[14];
    const float* W3   = (const float*)d_in[15];
    float* out = (float*)d_out;

    char* p = (char*)d_ws;
    unsigned short* hs = (unsigned short*)p;  p += (size_t)N_NODES * 32 * 2;   // 6.4MB
    char* aggraw = p;                         p += (size_t)N_NODES * 128 * 4;  // 51.2MB (f32-capable)
    unsigned short* agg_bf = (unsigned short*)aggraw;
    float*          agg_f  = (float*)aggraw;
    float* jet1 = (float*)p;                  p += 1024 * 64 * 4;
    float* jet2 = (float*)p;                  p += 1024 * 128 * 4;
    float* jet3 = (float*)p;                  p += 1024 * 128 * 4;
    float* sc1 = (float*)p; p += 64 * 4;  float* sh1 = (float*)p; p += 64 * 4;
    float* sc2 = (float*)p; p += 128 * 4; float* sh2 = (float*)p; p += 128 * 4;
    float* sc3 = (float*)p; p += 128 * 4; float* sh3 = (float*)p; p += 128 * 4;
    int* cnt_e    = (int*)p; p += (size_t)N_NODES * 4;
    int* base_e   = (int*)p; p += (size_t)N_NODES * 4;
    int* cursor_e = (int*)p; p += (size_t)N_NODES * 4;
    int* part     = (int*)p; p += 1024 * 4;
    int* cntI     = (int*)p; p += 1024 * 4;
    int* baseI    = (int*)p; p += 1024 * 4;
    int* cursorI  = (int*)p; p += 1024 * 4;
    int* order    = (int*)p; p += (size_t)N_NODES * 4;
    unsigned* hb  = (unsigned*)p; p += (size_t)N_EDGES * 4;   // 6.4MB (tier2: eid)
    size_t need_t2 = (size_t)(p - (char*)d_ws);
    int* cnt_cb   = (int*)p; p += (size_t)NCB * 4;            // 307KB
    int* cbase    = (int*)p; p += (size_t)NCB * 4;
    int* ccur     = (int*)p; p += (size_t)NCB * 4;
    int*   tail_s = (int*)p;   p += (size_t)N_EDGES * 4;      // 6.4MB
    float* pf_s   = (float*)p; p += (size_t)N_EDGES * 16;     // 25.6MB
    size_t need_t1 = (size_t)(p - (char*)d_ws);
    int tier = (ws_size >= need_t1) ? 1 : (ws_size >= need_t2) ? 2 : 3;

    // ---- indicator-CSR (atomic-free jets) ----
    hipMemsetAsync(cntI, 0, 1024 * sizeof(int), stream);
    countI_kernel<<<(N_NODES + 255) / 256, 256, 0, stream>>>(ind, cntI);
    scanB_kernel<<<1, 1024, 0, stream>>>(cntI, baseI, cursorI, 1024);
    scatterI_kernel<<<(N_NODES + 255) / 256, 256, 0, stream>>>(ind, cursorI, order);

    // ---- BN1 stats ----
    bucket_jet_kernel<64><<<1024, 256, 0, stream>>>(x, w, order, baseI, cntI, jet1);
    stats_kernel<64><<<64, 256, 0, stream>>>(jet1, g1, b1, sc1, sh1);

    // ---- shortcut + layer1 (MFMA) ----
    fused1_kernel<<<(N_NODES + TILE1 - 1) / TILE1, 256, 0, stream>>>(
        x, w, sc1, sh1, Wsc, W1, hs, out);

    // ---- edge message passing ----
    if (tier <= 2) {
        hipMemsetAsync(cnt_e, 0, N_NODES * sizeof(int), stream);
        countBoth_kernel<<<NBA, 256, 0, stream>>>(head, cnt_e, cnt_cb);
        scanA_kernel<<<SNBLK, SCHUNK, 0, stream>>>(cnt_e, part, N_NODES);
        scanB_kernel<<<1, 1024, 0, stream>>>(part, part, nullptr, SNBLK);
        scanC_kernel<<<SNBLK, SCHUNK, 0, stream>>>(cnt_e, part, base_e, cursor_e, N_NODES);
        if (tier == 1) {
            scanA_kernel<<<SNB2, SCHUNK, 0, stream>>>(cnt_cb, part, NCB);
            scanB_kernel<<<1, 1024, 0, stream>>>(part, part, nullptr, SNB2);
            scanC_kernel<<<SNB2, SCHUNK, 0, stream>>>(cnt_cb, part, cbase, ccur, NCB);
            binC_kernel<<<NBA, 256, 0, stream>>>(head, cbase, hb);
            sortD_kernel<<<NBUK, 256, 0, stream>>>(cbase, base_e, hb, tail, pf,
                                                   tail_s, pf_s);
            gather2_kernel<1><<<(N_NODES + 3) / 4, 256, 0, stream>>>(
                base_e, cnt_e, tail_s, pf_s, nullptr, tail, pf, hs, agg_bf);
        } else {
            escatterE_kernel<<<(N_EDGES + 255) / 256, 256, 0, stream>>>(
                head, cursor_e, (int*)hb);
            gather2_kernel<0><<<(N_NODES + 3) / 4, 256, 0, stream>>>(
                base_e, cnt_e, nullptr, nullptr, (int*)hb, tail, pf, hs, agg_bf);
        }
        // ---- BN2 + layer2 (bf16 in-place) ----
        bucket_jet_bf128_kernel<<<1024, 256, 0, stream>>>(agg_bf, w, order, baseI, cntI, jet2);
        stats_kernel<128><<<128, 256, 0, stream>>>(jet2, g2, b2, sc2, sh2);
        fused2_kernel<1, 1><<<(N_NODES + TILE2 - 1) / TILE2, 256, 0, stream>>>(
            agg_bf, sc2, sh2, W2, agg_bf, nullptr);
        // ---- BN3 + layer3 + shortcut add ----
        bucket_jet_bf128_kernel<<<1024, 256, 0, stream>>>(agg_bf, w, order, baseI, cntI, jet3);
        stats_kernel<128><<<128, 256, 0, stream>>>(jet3, g3, b3, sc3, sh3);
        fused2_kernel<1, 0><<<(N_NODES + TILE2 - 1) / TILE2, 256, 0, stream>>>(
            agg_bf, sc3, sh3, W3, out, out);
    } else {
        // tier-3: f32 atomic fallback pipeline
        hipMemsetAsync(agg_f, 0, (size_t)N_NODES * 128 * sizeof(float), stream);
        edge_kernel<<<(int)(((long long)N_EDGES * 128) / 256), 256, 0, stream>>>(
            head, tail, pf, hs, agg_f);
        bucket_jet_kernel<128><<<1024, 256, 0, stream>>>(agg_f, w, order, baseI, cntI, jet2);
        stats_kernel<128><<<128, 256, 0, stream>>>(jet2, g2, b2, sc2, sh2);
        fused2_kernel<0, 0><<<(N_NODES + TILE2 - 1) / TILE2, 256, 0, stream>>>(
            agg_f, sc2, sh2, W2, agg_f, nullptr);
        bucket_jet_kernel<128><<<1024, 256, 0, stream>>>(agg_f, w, order, baseI, cntI, jet3);
        stats_kernel<128><<<128, 256, 0, stream>>>(jet3, g3, b3, sc3, sh3);
        fused2_kernel<0, 0><<<(N_NODES + TILE2 - 1) / TILE2, 256, 0, stream>>>(
            agg_f, sc3, sh3, W3, out, out);
    }

    (void)in_sizes; (void)n_in; (void)out_size;
}

// Round 9
// 429.363 us; speedup vs baseline: 1.6929x; 1.0915x over previous
//
#include <hip/hip_runtime.h>

#define N_NODES 100000
#define N_EDGES 1600000
#define NB      1024
#define EPSF    1e-5f

#define SCHUNK 128
#define SNBLK ((N_NODES + SCHUNK - 1) / SCHUNK)   // 782

#define BUK_SH  7
#define NBUK    ((N_NODES + 127) >> 7)            // 782 buckets of 128 heads
#define EPB     16384
#define NBA     ((N_EDGES + EPB - 1) / EPB)       // 98 binning blocks
#define NCB     (NBUK * NBA)                      // 76,636 count-matrix entries
#define SNB2    ((NCB + SCHUNK - 1) / SCHUNK)     // 599

typedef float f32x4  __attribute__((ext_vector_type(4)));
typedef short bf16x8 __attribute__((ext_vector_type(8)));

__device__ __forceinline__ float bf2f(unsigned short u) {
    union { unsigned int i; float f; } v; v.i = ((unsigned int)u) << 16; return v.f;
}
__device__ __forceinline__ unsigned short f2bf(float f) {
    union { float ff; unsigned int i; } v; v.ff = f;
    unsigned int r = v.i + 0x7FFFu + ((v.i >> 16) & 1u);   // RNE
    return (unsigned short)(r >> 16);
}

// -------------- per-channel mean/var(ddof=1) -> scale/shift --------------
template<int C>
__global__ __launch_bounds__(256) void stats_kernel(const float* __restrict__ jet,
                                                    const float* __restrict__ g,
                                                    const float* __restrict__ b,
                                                    float* __restrict__ scale,
                                                    float* __restrict__ shift) {
    int c = blockIdx.x;
    int t = threadIdx.x;
    float s = 0.f, s2 = 0.f;
    for (int r = t; r < NB; r += 256) {
        float v = jet[r * C + c];
        s += v; s2 += v * v;
    }
    __shared__ float ls[256], ls2[256];
    ls[t] = s; ls2[t] = s2;
    __syncthreads();
    for (int ofs = 128; ofs > 0; ofs >>= 1) {
        if (t < ofs) { ls[t] += ls[t + ofs]; ls2[t] += ls2[t + ofs]; }
        __syncthreads();
    }
    if (t == 0) {
        float mean = ls[0] / (float)NB;
        float var  = (ls2[0] - (float)NB * mean * mean) / (float)(NB - 1);
        float sc   = g[c] / sqrtf(var + EPSF);
        scale[c] = sc;
        shift[c] = b[c] - mean * sc;
    }
}

// ---------------- count kernels ------------------------------------------
__global__ __launch_bounds__(256) void countI_kernel(const int* __restrict__ ind,
                                                     int* __restrict__ cntI) {
    int n = blockIdx.x * 256 + threadIdx.x;
    if (n < N_NODES) atomicAdd(&cntI[ind[n]], 1);
}

// merged: per-head counts (global atomics) + per-(bucket,block) histogram
__global__ __launch_bounds__(256) void countBoth_kernel(const int* __restrict__ head,
                                                        int* __restrict__ cnt_e,
                                                        int* __restrict__ cnt_cb) {
    __shared__ int h[NBUK];
    int tid = threadIdx.x;
    int blk = blockIdx.x;
    for (int i = tid; i < NBUK; i += 256) h[i] = 0;
    __syncthreads();
    int e0 = blk * EPB;
    for (int k = tid; k < EPB; k += 256) {
        int e = e0 + k;
        if (e < N_EDGES) {
            int hd = head[e];
            atomicAdd(&cnt_e[hd], 1);
            atomicAdd(&h[hd >> BUK_SH], 1);
        }
    }
    __syncthreads();
    for (int i = tid; i < NBUK; i += 256) cnt_cb[i * NBA + blk] = h[i];
}

// ---------------- scans ---------------------------------------------------
__global__ __launch_bounds__(SCHUNK) void scanA_kernel(const int* __restrict__ cnt,
                                                       int* __restrict__ part, int n) {
    __shared__ int ls[SCHUNK];
    int t = threadIdx.x;
    int i = blockIdx.x * SCHUNK + t;
    ls[t] = (i < n) ? cnt[i] : 0;
    __syncthreads();
    for (int ofs = SCHUNK / 2; ofs > 0; ofs >>= 1) {
        if (t < ofs) ls[t] += ls[t + ofs];
        __syncthreads();
    }
    if (t == 0) part[blockIdx.x] = ls[0];
}

// single-block scan (n <= 1024); EXCLUSIVE prefix to out (and out2)
__global__ __launch_bounds__(1024) void scanB_kernel(const int* __restrict__ in,
                                                     int* __restrict__ out,
                                                     int* __restrict__ out2, int n) {
    __shared__ int ls[1024];
    int t = threadIdx.x;
    int v = (t < n) ? in[t] : 0;
    ls[t] = v;
    __syncthreads();
    for (int ofs = 1; ofs < 1024; ofs <<= 1) {
        int u = (t >= ofs) ? ls[t - ofs] : 0;
        __syncthreads();
        ls[t] += u;
        __syncthreads();
    }
    if (t < n) {
        int e = ls[t] - v;
        out[t] = e;
        if (out2) out2[t] = e;
    }
}

__global__ __launch_bounds__(SCHUNK) void scanC_kernel(const int* __restrict__ cnt,
                                                       const int* __restrict__ poff,
                                                       int* __restrict__ base,
                                                       int* __restrict__ cursor, int n) {
    __shared__ int ls[SCHUNK];
    int t = threadIdx.x;
    int i = blockIdx.x * SCHUNK + t;
    int v = (i < n) ? cnt[i] : 0;
    ls[t] = v;
    __syncthreads();
    for (int ofs = 1; ofs < SCHUNK; ofs <<= 1) {
        int u = (t >= ofs) ? ls[t - ofs] : 0;
        __syncthreads();
        ls[t] += u;
        __syncthreads();
    }
    if (i < n) {
        int bse = poff[blockIdx.x] + ls[t] - v;
        base[i] = bse;
        cursor[i] = bse;
    }
}

// ---- Pass C: bin packed records (eid | head_low<<21) into bucket chunks --
__global__ __launch_bounds__(256) void binC_kernel(const int* __restrict__ head,
                                                   const int* __restrict__ cbase,
                                                   unsigned* __restrict__ hb) {
    __shared__ int cur[NBUK];
    int tid = threadIdx.x;
    int blk = blockIdx.x;
    for (int i = tid; i < NBUK; i += 256) cur[i] = cbase[i * NBA + blk];
    __syncthreads();
    int e0 = blk * EPB;
    for (int k = tid; k < EPB; k += 256) {
        int e = e0 + k;
        if (e < N_EDGES) {
            int hd = head[e];
            int b = hd >> BUK_SH;
            int slot = atomicAdd(&cur[b], 1);
            hb[slot] = (unsigned)e | ((unsigned)(hd & 127) << 21);
        }
    }
}

// ---- Pass D: within-bucket CSR placement; random READS, clean writes ----
// pf converted to bf16x4 (8B/slot) on the way through
__global__ __launch_bounds__(256) void sortD_kernel(const int* __restrict__ cbase,
                                                    const int* __restrict__ base_e,
                                                    const unsigned* __restrict__ hb,
                                                    const int* __restrict__ tail,
                                                    const float* __restrict__ pf,
                                                    int* __restrict__ tail_s,
                                                    uint2* __restrict__ pf_s8) {
    __shared__ int hcur[128];
    int tid = threadIdx.x;
    int b = blockIdx.x;
    int h0 = b << BUK_SH;
    if (tid < 128) {
        int h = h0 + tid;
        hcur[tid] = (h < N_NODES) ? base_e[h] : 0;
    }
    __syncthreads();
    int lo = cbase[b * NBA];
    int hi = (b + 1 < NBUK) ? cbase[(b + 1) * NBA] : N_EDGES;
    for (int k = lo + tid; k < hi; k += 256) {
        unsigned rec = hb[k];
        int e = (int)(rec & 0x1FFFFFu);
        int h7 = (int)(rec >> 21);
        int slot = atomicAdd(&hcur[h7], 1);
        float4 pv = ((const float4*)pf)[e];
        uint2 pk;
        pk.x = (unsigned)f2bf(pv.x) | ((unsigned)f2bf(pv.y) << 16);
        pk.y = (unsigned)f2bf(pv.z) | ((unsigned)f2bf(pv.w) << 16);
        tail_s[slot] = tail[e];
        pf_s8[slot] = pk;
    }
}

// ---------------- legacy scatter (tier-2 fallback) -----------------------
__global__ __launch_bounds__(256) void escatterE_kernel(const int* __restrict__ head,
                                                        int* __restrict__ cursor,
                                                        int* __restrict__ eid) {
    int e = blockIdx.x * 256 + threadIdx.x;
    if (e >= N_EDGES) return;
    int slot = atomicAdd(&cursor[head[e]], 1);
    eid[slot] = e;
}

__global__ __launch_bounds__(256) void scatterI_kernel(const int* __restrict__ ind,
                                                       int* __restrict__ cursorI,
                                                       int* __restrict__ order) {
    int n = blockIdx.x * 256 + threadIdx.x;
    if (n < N_NODES) {
        int pos = atomicAdd(&cursorI[ind[n]], 1);
        order[pos] = n;
    }
}

// ---------- bucket jet (f32 input): jet[b,c] = sum x[n,c]*w[n] -----------
template<int C>
__global__ __launch_bounds__(256) void bucket_jet_kernel(const float* __restrict__ xx,
                                                         const float* __restrict__ w,
                                                         const int* __restrict__ order,
                                                         const int* __restrict__ baseI,
                                                         const int* __restrict__ cntI,
                                                         float* __restrict__ jet) {
    constexpr int G = 256 / C;
    __shared__ float red[256];
    int b = blockIdx.x;
    int g = threadIdx.x / C;
    int c = threadIdx.x % C;
    int s0 = baseI[b], m = cntI[b];
    float s = 0.f;
    for (int k = g; k < m; k += G) {
        int n = order[s0 + k];
        s += xx[(size_t)n * C + c] * w[n];
    }
    red[threadIdx.x] = s;
    __syncthreads();
    for (int half = G / 2; half > 0; half >>= 1) {
        if (g < half) red[g * C + c] += red[(g + half) * C + c];
        __syncthreads();
    }
    if (g == 0) jet[b * C + c] = red[c];
}

// ---------- bucket jet (bf16 input, C=128): uint-packed reads ------------
__global__ __launch_bounds__(256) void bucket_jet_bf128_kernel(const unsigned short* __restrict__ xx,
                                                               const float* __restrict__ w,
                                                               const int* __restrict__ order,
                                                               const int* __restrict__ baseI,
                                                               const int* __restrict__ cntI,
                                                               float* __restrict__ jet) {
    __shared__ float redA[256], redB[256];
    int b = blockIdx.x;
    int g  = threadIdx.x >> 6;     // 4 groups
    int c2 = threadIdx.x & 63;     // channel pair
    int s0 = baseI[b], m = cntI[b];
    float a0 = 0.f, a1 = 0.f;
    for (int k = g; k < m; k += 4) {
        int n = order[s0 + k];
        float wn = w[n];
        unsigned u = ((const unsigned*)xx)[(size_t)n * 64 + c2];
        a0 += bf2f((unsigned short)(u & 0xFFFFu)) * wn;
        a1 += bf2f((unsigned short)(u >> 16)) * wn;
    }
    redA[threadIdx.x] = a0; redB[threadIdx.x] = a1;
    __syncthreads();
    for (int half = 2; half > 0; half >>= 1) {
        if (g < half) {
            redA[g * 64 + c2] += redA[(g + half) * 64 + c2];
            redB[g * 64 + c2] += redB[(g + half) * 64 + c2];
        }
        __syncthreads();
    }
    if (g == 0) {
        jet[b * 128 + 2 * c2]     = redA[c2];
        jet[b * 128 + 2 * c2 + 1] = redB[c2];
    }
}

// --------- fused1 MFMA: hs = (relu(bn1(x)) @ W1^T) * w  (hs only) --------
#define TILE1 64
__global__ __launch_bounds__(256) void fused1_kernel(const float* __restrict__ x,
                                                     const float* __restrict__ w,
                                                     const float* __restrict__ scale,
                                                     const float* __restrict__ shift,
                                                     const float* __restrict__ W1,
                                                     unsigned short* __restrict__ hs) {
    __shared__ __align__(16) unsigned short xnb[TILE1 * 64];   // 8KB
    __shared__ __align__(16) unsigned short w1b[32 * 64];      // 4KB
    int tid = threadIdx.x;
    int n0  = blockIdx.x * TILE1;
    char* xnb_ = (char*)xnb; char* w1b_ = (char*)w1b;

    for (int idx = tid; idx < TILE1 * 8; idx += 256) {
        int r = idx >> 3, c0 = (idx & 7) << 3;
        int n = n0 + r;
        float4 vA = make_float4(0.f, 0.f, 0.f, 0.f), vB = vA;
        if (n < N_NODES) {
            vA = *(const float4*)&x[(size_t)n * 64 + c0];
            vB = *(const float4*)&x[(size_t)n * 64 + c0 + 4];
        }
        float4 scA = *(const float4*)&scale[c0], scB = *(const float4*)&scale[c0 + 4];
        float4 shA = *(const float4*)&shift[c0], shB = *(const float4*)&shift[c0 + 4];
        unsigned short na[8];
        na[0] = f2bf(fmaxf(fmaf(vA.x, scA.x, shA.x), 0.f));
        na[1] = f2bf(fmaxf(fmaf(vA.y, scA.y, shA.y), 0.f));
        na[2] = f2bf(fmaxf(fmaf(vA.z, scA.z, shA.z), 0.f));
        na[3] = f2bf(fmaxf(fmaf(vA.w, scA.w, shA.w), 0.f));
        na[4] = f2bf(fmaxf(fmaf(vB.x, scB.x, shB.x), 0.f));
        na[5] = f2bf(fmaxf(fmaf(vB.y, scB.y, shB.y), 0.f));
        na[6] = f2bf(fmaxf(fmaf(vB.z, scB.z, shB.z), 0.f));
        na[7] = f2bf(fmaxf(fmaf(vB.w, scB.w, shB.w), 0.f));
        int byte = ((r << 7) + ((idx & 7) << 4)) ^ ((r & 7) << 4);
        *(bf16x8*)(xnb_ + byte) = *(bf16x8*)na;
    }
    for (int idx = tid; idx < 32 * 8; idx += 256) {
        int r = idx >> 3, c0 = (idx & 7) << 3;
        float4 vA = *(const float4*)&W1[(size_t)r * 64 + c0];
        float4 vB = *(const float4*)&W1[(size_t)r * 64 + c0 + 4];
        unsigned short ua[8];
        ua[0] = f2bf(vA.x); ua[1] = f2bf(vA.y); ua[2] = f2bf(vA.z); ua[3] = f2bf(vA.w);
        ua[4] = f2bf(vB.x); ua[5] = f2bf(vB.y); ua[6] = f2bf(vB.z); ua[7] = f2bf(vB.w);
        int byte = ((r << 7) + ((idx & 7) << 4)) ^ ((r & 7) << 4);
        *(bf16x8*)(w1b_ + byte) = *(bf16x8*)ua;
    }
    __syncthreads();

    int wv   = tid >> 6;
    int lane = tid & 63;
    int l15  = lane & 15;
    int lhi  = lane >> 4;

    f32x4 acc[2];
    acc[0] = (f32x4){0.f, 0.f, 0.f, 0.f};
    acc[1] = (f32x4){0.f, 0.f, 0.f, 0.f};

#pragma unroll
    for (int ks = 0; ks < 2; ks++) {
        int rA = (wv << 4) + l15;
        int byteA = ((rA << 7) + (ks << 6) + (lhi << 4)) ^ ((rA & 7) << 4);
        bf16x8 a = *(const bf16x8*)(xnb_ + byteA);
#pragma unroll
        for (int cf = 0; cf < 2; cf++) {
            int rB = (cf << 4) + l15;
            int byteB = ((rB << 7) + (ks << 6) + (lhi << 4)) ^ ((rB & 7) << 4);
            bf16x8 b = *(const bf16x8*)(w1b_ + byteB);
            acc[cf] = __builtin_amdgcn_mfma_f32_16x16x32_bf16(a, b, acc[cf], 0, 0, 0);
        }
    }

#pragma unroll
    for (int cf = 0; cf < 2; cf++) {
        int co = (cf << 4) + l15;
#pragma unroll
        for (int j = 0; j < 4; j++) {
            int n = n0 + (wv << 4) + (lhi << 2) + j;
            if (n < N_NODES) hs[(size_t)n * 32 + co] = f2bf(acc[cf][j] * w[n]);
        }
    }
}

// ---------- gather: one wave per node, lane = channel pair; bf16 out -----
template<int PRE>
__global__ __launch_bounds__(256) void gather2_kernel(const int* __restrict__ base,
                                                      const int* __restrict__ cnt,
                                                      const int* __restrict__ tail_s,
                                                      const unsigned* __restrict__ pf_s8,
                                                      const int* __restrict__ eid,
                                                      const int* __restrict__ tail,
                                                      const float* __restrict__ pf,
                                                      const unsigned short* __restrict__ hs,
                                                      unsigned short* __restrict__ agg) {
    int n = blockIdx.x * 4 + (threadIdx.x >> 6);
    if (n >= N_NODES) return;
    int lane = threadIdx.x & 63;
    int i = lane >> 1;
    int half = lane & 1;          // pf word index (channels 2*half, 2*half+1)
    int s0 = base[n], c = cnt[n];
    float a0 = 0.f, a1 = 0.f;
    int k = 0;
    for (; k + 4 <= c; k += 4) {
        int t0, t1, t2, t3;
        float2 p0, p1, p2, p3;
        if (PRE) {
            t0 = tail_s[s0 + k];     t1 = tail_s[s0 + k + 1];
            t2 = tail_s[s0 + k + 2]; t3 = tail_s[s0 + k + 3];
            unsigned u0 = pf_s8[(size_t)(s0 + k) * 2 + half];
            unsigned u1 = pf_s8[(size_t)(s0 + k + 1) * 2 + half];
            unsigned u2 = pf_s8[(size_t)(s0 + k + 2) * 2 + half];
            unsigned u3 = pf_s8[(size_t)(s0 + k + 3) * 2 + half];
            p0 = make_float2(bf2f((unsigned short)(u0 & 0xFFFFu)), bf2f((unsigned short)(u0 >> 16)));
            p1 = make_float2(bf2f((unsigned short)(u1 & 0xFFFFu)), bf2f((unsigned short)(u1 >> 16)));
            p2 = make_float2(bf2f((unsigned short)(u2 & 0xFFFFu)), bf2f((unsigned short)(u2 >> 16)));
            p3 = make_float2(bf2f((unsigned short)(u3 & 0xFFFFu)), bf2f((unsigned short)(u3 >> 16)));
        } else {
            int e0 = eid[s0 + k],     e1 = eid[s0 + k + 1];
            int e2 = eid[s0 + k + 2], e3 = eid[s0 + k + 3];
            t0 = tail[e0]; t1 = tail[e1]; t2 = tail[e2]; t3 = tail[e3];
            p0 = *(const float2*)&pf[(size_t)e0 * 4 + half * 2];
            p1 = *(const float2*)&pf[(size_t)e1 * 4 + half * 2];
            p2 = *(const float2*)&pf[(size_t)e2 * 4 + half * 2];
            p3 = *(const float2*)&pf[(size_t)e3 * 4 + half * 2];
        }
        float h0 = bf2f(hs[(size_t)t0 * 32 + i]);
        float h1 = bf2f(hs[(size_t)t1 * 32 + i]);
        float h2 = bf2f(hs[(size_t)t2 * 32 + i]);
        float h3 = bf2f(hs[(size_t)t3 * 32 + i]);
        a0 += h0 * p0.x; a1 += h0 * p0.y;
        a0 += h1 * p1.x; a1 += h1 * p1.y;
        a0 += h2 * p2.x; a1 += h2 * p2.y;
        a0 += h3 * p3.x; a1 += h3 * p3.y;
    }
    for (; k < c; k++) {
        int t0; float2 p0;
        if (PRE) {
            t0 = tail_s[s0 + k];
            unsigned u0 = pf_s8[(size_t)(s0 + k) * 2 + half];
            p0 = make_float2(bf2f((unsigned short)(u0 & 0xFFFFu)), bf2f((unsigned short)(u0 >> 16)));
        } else {
            int e0 = eid[s0 + k];
            t0 = tail[e0];
            p0 = *(const float2*)&pf[(size_t)e0 * 4 + half * 2];
        }
        float h0 = bf2f(hs[(size_t)t0 * 32 + i]);
        a0 += h0 * p0.x; a1 += h0 * p0.y;
    }
    unsigned pk = (unsigned)f2bf(a0) | ((unsigned)f2bf(a1) << 16);
    ((unsigned*)agg)[(size_t)n * 64 + lane] = pk;
}

// -------- legacy atomic edge scatter (tier-3, f32 agg) -------------------
__global__ __launch_bounds__(256) void edge_kernel(const int* __restrict__ head,
                                                   const int* __restrict__ tail,
                                                   const float* __restrict__ pf,
                                                   const unsigned short* __restrict__ hs,
                                                   float* __restrict__ agg) {
    long long tid = (long long)blockIdx.x * 256 + threadIdx.x;
    if (tid >= (long long)N_EDGES * 128) return;
    int e = (int)(tid >> 7);
    int j = (int)(tid & 127);
    int i = j >> 2, t = j & 3;
    float v = bf2f(hs[(size_t)tail[e] * 32 + i]) * pf[(size_t)e * 4 + t];
    atomicAdd(&agg[(size_t)head[e] * 128 + j], v);
}

// ------- fused2 MFMA: y = relu(bn(x)) @ W^T, in-place safe ---------------
#define TILE2 64
template<int INBF, int OUTBF>
__global__ __launch_bounds__(256) void fused2_kernel(const void* __restrict__ xin_,
                                                     const float* __restrict__ scale,
                                                     const float* __restrict__ shift,
                                                     const float* __restrict__ W,
                                                     void* __restrict__ yout_) {
    __shared__ __align__(16) unsigned short xnb[TILE2 * 128];   // 16KB
    __shared__ __align__(16) unsigned short wb[128 * 128];      // 32KB
    int tid = threadIdx.x;
    int n0  = blockIdx.x * TILE2;
    char* xbase = (char*)xnb;
    char* wbase = (char*)wb;

    for (int idx = tid; idx < TILE2 * 16; idx += 256) {
        int r = idx >> 4;
        int c0 = (idx & 15) << 3;
        int n = n0 + r;
        float f[8];
        if (n < N_NODES) {
            if (INBF) {
                const unsigned short* xu = (const unsigned short*)xin_;
                uint4 U = *(const uint4*)(xu + (size_t)n * 128 + c0);
                f[0] = bf2f((unsigned short)(U.x & 0xFFFFu)); f[1] = bf2f((unsigned short)(U.x >> 16));
                f[2] = bf2f((unsigned short)(U.y & 0xFFFFu)); f[3] = bf2f((unsigned short)(U.y >> 16));
                f[4] = bf2f((unsigned short)(U.z & 0xFFFFu)); f[5] = bf2f((unsigned short)(U.z >> 16));
                f[6] = bf2f((unsigned short)(U.w & 0xFFFFu)); f[7] = bf2f((unsigned short)(U.w >> 16));
            } else {
                const float* xf = (const float*)xin_;
                float4 vA = *(const float4*)&xf[(size_t)n * 128 + c0];
                float4 vB = *(const float4*)&xf[(size_t)n * 128 + c0 + 4];
                f[0] = vA.x; f[1] = vA.y; f[2] = vA.z; f[3] = vA.w;
                f[4] = vB.x; f[5] = vB.y; f[6] = vB.z; f[7] = vB.w;
            }
        } else {
#pragma unroll
            for (int q = 0; q < 8; q++) f[q] = 0.f;
        }
        unsigned short ua[8];
#pragma unroll
        for (int q = 0; q < 8; q++)
            ua[q] = f2bf(fmaxf(fmaf(f[q], scale[c0 + q], shift[c0 + q]), 0.f));
        int byte = ((r << 8) + ((idx & 15) << 4)) ^ ((r & 7) << 4);
        *(bf16x8*)(xbase + byte) = *(bf16x8*)ua;
    }
    for (int idx = tid; idx < 128 * 16; idx += 256) {
        int r = idx >> 4;
        int c0 = (idx & 15) << 3;
        float4 vA = *(const float4*)&W[(size_t)r * 128 + c0];
        float4 vB = *(const float4*)&W[(size_t)r * 128 + c0 + 4];
        unsigned short ua[8];
        ua[0] = f2bf(vA.x); ua[1] = f2bf(vA.y); ua[2] = f2bf(vA.z); ua[3] = f2bf(vA.w);
        ua[4] = f2bf(vB.x); ua[5] = f2bf(vB.y); ua[6] = f2bf(vB.z); ua[7] = f2bf(vB.w);
        int byte = ((r << 8) + ((idx & 15) << 4)) ^ ((r & 7) << 4);
        *(bf16x8*)(wbase + byte) = *(bf16x8*)ua;
    }
    __syncthreads();

    int wv   = tid >> 6;
    int lane = tid & 63;
    int l15  = lane & 15;
    int lhi  = lane >> 4;

    f32x4 acc[8];
#pragma unroll
    for (int cf = 0; cf < 8; cf++) acc[cf] = (f32x4){0.f, 0.f, 0.f, 0.f};

#pragma unroll
    for (int ks = 0; ks < 4; ks++) {
        int rA = (wv << 4) + l15;
        int byteA = ((rA << 8) + (ks << 6) + (lhi << 4)) ^ ((rA & 7) << 4);
        bf16x8 a = *(const bf16x8*)(xbase + byteA);
#pragma unroll
        for (int cf = 0; cf < 8; cf++) {
            int rB = (cf << 4) + l15;
            int byteB = ((rB << 8) + (ks << 6) + (lhi << 4)) ^ ((rB & 7) << 4);
            bf16x8 b = *(const bf16x8*)(wbase + byteB);
            acc[cf] = __builtin_amdgcn_mfma_f32_16x16x32_bf16(a, b, acc[cf], 0, 0, 0);
        }
    }

#pragma unroll
    for (int cf = 0; cf < 8; cf++) {
        int col = (cf << 4) + l15;
#pragma unroll
        for (int j = 0; j < 4; j++) {
            int n = n0 + (wv << 4) + (lhi << 2) + j;
            if (n < N_NODES) {
                float v = acc[cf][j];
                if (OUTBF) ((unsigned short*)yout_)[(size_t)n * 128 + col] = f2bf(v);
                else       ((float*)yout_)[(size_t)n * 128 + col] = v;
            }
        }
    }
}

// ------- fused3 dual-GEMM: out = relu(bn3(h2)) @ W3^T + x @ Wsc^T --------
template<int INBF>
__global__ __launch_bounds__(256) void fused3_kernel(const void* __restrict__ h2_,
                                                     const float* __restrict__ x,
                                                     const float* __restrict__ scale,
                                                     const float* __restrict__ shift,
                                                     const float* __restrict__ Wsc,
                                                     const float* __restrict__ W3,
                                                     float* __restrict__ out) {
    __shared__ __align__(16) unsigned short xnb[TILE2 * 128];   // 16KB (h2 normed)
    __shared__ __align__(16) unsigned short xrb[TILE2 * 64];    // 8KB  (x raw)
    __shared__ __align__(16) unsigned short wb[128 * 128];      // 32KB (Wsc then W3)
    int tid = threadIdx.x;
    int n0  = blockIdx.x * TILE2;
    char* xbase = (char*)xnb;
    char* rbase = (char*)xrb;
    char* wbase = (char*)wb;

    // stage normalized h2 (128 cols)
    for (int idx = tid; idx < TILE2 * 16; idx += 256) {
        int r = idx >> 4;
        int c0 = (idx & 15) << 3;
        int n = n0 + r;
        float f[8];
        if (n < N_NODES) {
            if (INBF) {
                const unsigned short* xu = (const unsigned short*)h2_;
                uint4 U = *(const uint4*)(xu + (size_t)n * 128 + c0);
                f[0] = bf2f((unsigned short)(U.x & 0xFFFFu)); f[1] = bf2f((unsigned short)(U.x >> 16));
                f[2] = bf2f((unsigned short)(U.y & 0xFFFFu)); f[3] = bf2f((unsigned short)(U.y >> 16));
                f[4] = bf2f((unsigned short)(U.z & 0xFFFFu)); f[5] = bf2f((unsigned short)(U.z >> 16));
                f[6] = bf2f((unsigned short)(U.w & 0xFFFFu)); f[7] = bf2f((unsigned short)(U.w >> 16));
            } else {
                const float* xf = (const float*)h2_;
                float4 vA = *(const float4*)&xf[(size_t)n * 128 + c0];
                float4 vB = *(const float4*)&xf[(size_t)n * 128 + c0 + 4];
                f[0] = vA.x; f[1] = vA.y; f[2] = vA.z; f[3] = vA.w;
                f[4] = vB.x; f[5] = vB.y; f[6] = vB.z; f[7] = vB.w;
            }
        } else {
#pragma unroll
            for (int q = 0; q < 8; q++) f[q] = 0.f;
        }
        unsigned short ua[8];
#pragma unroll
        for (int q = 0; q < 8; q++)
            ua[q] = f2bf(fmaxf(fmaf(f[q], scale[c0 + q], shift[c0 + q]), 0.f));
        int byte = ((r << 8) + ((idx & 15) << 4)) ^ ((r & 7) << 4);
        *(bf16x8*)(xbase + byte) = *(bf16x8*)ua;
    }
    // stage raw x (64 cols)
    for (int idx = tid; idx < TILE2 * 8; idx += 256) {
        int r = idx >> 3, c0 = (idx & 7) << 3;
        int n = n0 + r;
        float4 vA = make_float4(0.f, 0.f, 0.f, 0.f), vB = vA;
        if (n < N_NODES) {
            vA = *(const float4*)&x[(size_t)n * 64 + c0];
            vB = *(const float4*)&x[(size_t)n * 64 + c0 + 4];
        }
        unsigned short ua[8];
        ua[0] = f2bf(vA.x); ua[1] = f2bf(vA.y); ua[2] = f2bf(vA.z); ua[3] = f2bf(vA.w);
        ua[4] = f2bf(vB.x); ua[5] = f2bf(vB.y); ua[6] = f2bf(vB.z); ua[7] = f2bf(vB.w);
        int byte = ((r << 7) + ((idx & 7) << 4)) ^ ((r & 7) << 4);
        *(bf16x8*)(rbase + byte) = *(bf16x8*)ua;
    }
    // stage Wsc (128 rows x 64 cols) into wb
    for (int idx = tid; idx < 128 * 8; idx += 256) {
        int r = idx >> 3, c0 = (idx & 7) << 3;
        float4 vA = *(const float4*)&Wsc[(size_t)r * 64 + c0];
        float4 vB = *(const float4*)&Wsc[(size_t)r * 64 + c0 + 4];
        unsigned short ua[8];
        ua[0] = f2bf(vA.x); ua[1] = f2bf(vA.y); ua[2] = f2bf(vA.z); ua[3] = f2bf(vA.w);
        ua[4] = f2bf(vB.x); ua[5] = f2bf(vB.y); ua[6] = f2bf(vB.z); ua[7] = f2bf(vB.w);
        int byte = ((r << 7) + ((idx & 7) << 4)) ^ ((r & 7) << 4);
        *(bf16x8*)(wbase + byte) = *(bf16x8*)ua;
    }
    __syncthreads();

    int wv   = tid >> 6;
    int lane = tid & 63;
    int l15  = lane & 15;
    int lhi  = lane >> 4;

    f32x4 acc[8];
#pragma unroll
    for (int cf = 0; cf < 8; cf++) acc[cf] = (f32x4){0.f, 0.f, 0.f, 0.f};

    // phase A: shortcut (K=64, raw x @ Wsc)
#pragma unroll
    for (int ks = 0; ks < 2; ks++) {
        int rA = (wv << 4) + l15;
        int byteA = ((rA << 7) + (ks << 6) + (lhi << 4)) ^ ((rA & 7) << 4);
        bf16x8 a = *(const bf16x8*)(rbase + byteA);
#pragma unroll
        for (int cf = 0; cf < 8; cf++) {
            int rB = (cf << 4) + l15;
            int byteB = ((rB << 7) + (ks << 6) + (lhi << 4)) ^ ((rB & 7) << 4);
            bf16x8 b = *(const bf16x8*)(wbase + byteB);
            acc[cf] = __builtin_amdgcn_mfma_f32_16x16x32_bf16(a, b, acc[cf], 0, 0, 0);
        }
    }
    __syncthreads();
    // restage wb with W3 (128x128)
    for (int idx = tid; idx < 128 * 16; idx += 256) {
        int r = idx >> 4;
        int c0 = (idx & 15) << 3;
        float4 vA = *(const float4*)&W3[(size_t)r * 128 + c0];
        float4 vB = *(const float4*)&W3[(size_t)r * 128 + c0 + 4];
        unsigned short ua[8];
        ua[0] = f2bf(vA.x); ua[1] = f2bf(vA.y); ua[2] = f2bf(vA.z); ua[3] = f2bf(vA.w);
        ua[4] = f2bf(vB.x); ua[5] = f2bf(vB.y); ua[6] = f2bf(vB.z); ua[7] = f2bf(vB.w);
        int byte = ((r << 8) + ((idx & 15) << 4)) ^ ((r & 7) << 4);
        *(bf16x8*)(wbase + byte) = *(bf16x8*)ua;
    }
    __syncthreads();

    // phase B: main (K=128, normed h2 @ W3)
#pragma unroll
    for (int ks = 0; ks < 4; ks++) {
        int rA = (wv << 4) + l15;
        int byteA = ((rA << 8) + (ks << 6) + (lhi << 4)) ^ ((rA & 7) << 4);
        bf16x8 a = *(const bf16x8*)(xbase + byteA);
#pragma unroll
        for (int cf = 0; cf < 8; cf++) {
            int rB = (cf << 4) + l15;
            int byteB = ((rB << 8) + (ks << 6) + (lhi << 4)) ^ ((rB & 7) << 4);
            bf16x8 b = *(const bf16x8*)(wbase + byteB);
            acc[cf] = __builtin_amdgcn_mfma_f32_16x16x32_bf16(a, b, acc[cf], 0, 0, 0);
        }
    }

#pragma unroll
    for (int cf = 0; cf < 8; cf++) {
        int col = (cf << 4) + l15;
#pragma unroll
        for (int j = 0; j < 4; j++) {
            int n = n0 + (wv << 4) + (lhi << 2) + j;
            if (n < N_NODES) out[(size_t)n * 128 + col] = acc[cf][j];
        }
    }
}

extern "C" void kernel_launch(void* const* d_in, const int* in_sizes, int n_in,
                              void* d_out, int out_size, void* d_ws, size_t ws_size,
                              hipStream_t stream) {
    const float* x    = (const float*)d_in[0];
    const float* w    = (const float*)d_in[1];
    const float* pf   = (const float*)d_in[2];
    const int*   head = (const int*)d_in[3];
    const int*   tail = (const int*)d_in[4];
    const int*   ind  = (const int*)d_in[5];
    const float* Wsc  = (const float*)d_in[6];
    const float* g1   = (const float*)d_in[7];
    const float* b1   = (const float*)d_in[8];
    const float* W1   = (const float*)d_in[9];
    const float* g2   = (const float*)d_in[10];
    const float* b2   = (const float*)d_in[11];
    const float* W2   = (const float*)d_in[12];
    const float* g3   = (const float*)d_in[13];
    const float* b3   = (const float*)d_in[14];
    const float* W3   = (const float*)d_in[15];
    float* out = (float*)d_out;

    char* p = (char*)d_ws;
    unsigned short* hs = (unsigned short*)p;  p += (size_t)N_NODES * 32 * 2;   // 6.4MB
    char* aggraw = p;                         p += (size_t)N_NODES * 128 * 4;  // 51.2MB (f32-capable)
    unsigned short* agg_bf = (unsigned short*)aggraw;
    float*          agg_f  = (float*)aggraw;
    float* jet1 = (float*)p;                  p += 1024 * 64 * 4;
    float* jet2 = (float*)p;                  p += 1024 * 128 * 4;
    float* jet3 = (float*)p;                  p += 1024 * 128 * 4;
    float* sc1 = (float*)p; p += 64 * 4;  float* sh1 = (float*)p; p += 64 * 4;
    float* sc2 = (float*)p; p += 128 * 4; float* sh2 = (float*)p; p += 128 * 4;
    float* sc3 = (float*)p; p += 128 * 4; float* sh3 = (float*)p; p += 128 * 4;
    int* cnt_e    = (int*)p; p += (size_t)N_NODES * 4;
    int* base_e   = (int*)p; p += (size_t)N_NODES * 4;
    int* cursor_e = (int*)p; p += (size_t)N_NODES * 4;
    int* part     = (int*)p; p += 1024 * 4;
    int* cntI     = (int*)p; p += 1024 * 4;
    int* baseI    = (int*)p; p += 1024 * 4;
    int* cursorI  = (int*)p; p += 1024 * 4;
    int* order    = (int*)p; p += (size_t)N_NODES * 4;
    unsigned* hb  = (unsigned*)p; p += (size_t)N_EDGES * 4;   // 6.4MB (tier2: eid)
    size_t need_t2 = (size_t)(p - (char*)d_ws);
    int* cnt_cb   = (int*)p; p += (size_t)NCB * 4;            // 307KB
    int* cbase    = (int*)p; p += (size_t)NCB * 4;
    int* ccur     = (int*)p; p += (size_t)NCB * 4;
    int*   tail_s = (int*)p;   p += (size_t)N_EDGES * 4;      // 6.4MB
    uint2* pf_s8  = (uint2*)p; p += (size_t)N_EDGES * 8;      // 12.8MB
    size_t need_t1 = (size_t)(p - (char*)d_ws);
    int tier = (ws_size >= need_t1) ? 1 : (ws_size >= need_t2) ? 2 : 3;

    // ---- indicator-CSR (atomic-free jets) ----
    hipMemsetAsync(cntI, 0, 1024 * sizeof(int), stream);
    countI_kernel<<<(N_NODES + 255) / 256, 256, 0, stream>>>(ind, cntI);
    scanB_kernel<<<1, 1024, 0, stream>>>(cntI, baseI, cursorI, 1024);
    scatterI_kernel<<<(N_NODES + 255) / 256, 256, 0, stream>>>(ind, cursorI, order);

    // ---- BN1 stats ----
    bucket_jet_kernel<64><<<1024, 256, 0, stream>>>(x, w, order, baseI, cntI, jet1);
    stats_kernel<64><<<64, 256, 0, stream>>>(jet1, g1, b1, sc1, sh1);

    // ---- layer1 (hs only, MFMA) ----
    fused1_kernel<<<(N_NODES + TILE1 - 1) / TILE1, 256, 0, stream>>>(
        x, w, sc1, sh1, W1, hs);

    // ---- edge message passing ----
    if (tier <= 2) {
        hipMemsetAsync(cnt_e, 0, N_NODES * sizeof(int), stream);
        countBoth_kernel<<<NBA, 256, 0, stream>>>(head, cnt_e, cnt_cb);
        scanA_kernel<<<SNBLK, SCHUNK, 0, stream>>>(cnt_e, part, N_NODES);
        scanB_kernel<<<1, 1024, 0, stream>>>(part, part, nullptr, SNBLK);
        scanC_kernel<<<SNBLK, SCHUNK, 0, stream>>>(cnt_e, part, base_e, cursor_e, N_NODES);
        if (tier == 1) {
            scanA_kernel<<<SNB2, SCHUNK, 0, stream>>>(cnt_cb, part, NCB);
            scanB_kernel<<<1, 1024, 0, stream>>>(part, part, nullptr, SNB2);
            scanC_kernel<<<SNB2, SCHUNK, 0, stream>>>(cnt_cb, part, cbase, ccur, NCB);
            binC_kernel<<<NBA, 256, 0, stream>>>(head, cbase, hb);
            sortD_kernel<<<NBUK, 256, 0, stream>>>(cbase, base_e, hb, tail, pf,
                                                   tail_s, pf_s8);
            gather2_kernel<1><<<(N_NODES + 3) / 4, 256, 0, stream>>>(
                base_e, cnt_e, tail_s, (const unsigned*)pf_s8, nullptr, tail, pf, hs, agg_bf);
        } else {
            escatterE_kernel<<<(N_EDGES + 255) / 256, 256, 0, stream>>>(
                head, cursor_e, (int*)hb);
            gather2_kernel<0><<<(N_NODES + 3) / 4, 256, 0, stream>>>(
                base_e, cnt_e, nullptr, nullptr, (int*)hb, tail, pf, hs, agg_bf);
        }
        // ---- BN2 + layer2 (bf16 in-place) ----
        bucket_jet_bf128_kernel<<<1024, 256, 0, stream>>>(agg_bf, w, order, baseI, cntI, jet2);
        stats_kernel<128><<<128, 256, 0, stream>>>(jet2, g2, b2, sc2, sh2);
        fused2_kernel<1, 1><<<(N_NODES + TILE2 - 1) / TILE2, 256, 0, stream>>>(
            agg_bf, sc2, sh2, W2, agg_bf);
        // ---- BN3 + layer3 + shortcut (dual GEMM) ----
        bucket_jet_bf128_kernel<<<1024, 256, 0, stream>>>(agg_bf, w, order, baseI, cntI, jet3);
        stats_kernel<128><<<128, 256, 0, stream>>>(jet3, g3, b3, sc3, sh3);
        fused3_kernel<1><<<(N_NODES + TILE2 - 1) / TILE2, 256, 0, stream>>>(
            agg_bf, x, sc3, sh3, Wsc, W3, out);
    } else {
        // tier-3: f32 atomic fallback pipeline
        hipMemsetAsync(agg_f, 0, (size_t)N_NODES * 128 * sizeof(float), stream);
        edge_kernel<<<(int)(((long long)N_EDGES * 128) / 256), 256, 0, stream>>>(
            head, tail, pf, hs, agg_f);
        bucket_jet_kernel<128><<<1024, 256, 0, stream>>>(agg_f, w, order, baseI, cntI, jet2);
        stats_kernel<128><<<128, 256, 0, stream>>>(jet2, g2, b2, sc2, sh2);
        fused2_kernel<0, 0><<<(N_NODES + TILE2 - 1) / TILE2, 256, 0, stream>>>(
            agg_f, sc2, sh2, W2, agg_f);
        bucket_jet_kernel<128><<<1024, 256, 0, stream>>>(agg_f, w, order, baseI, cntI, jet3);
        stats_kernel<128><<<128, 256, 0, stream>>>(jet3, g3, b3, sc3, sh3);
        fused3_kernel<0><<<(N_NODES + TILE2 - 1) / TILE2, 256, 0, stream>>>(
            agg_f, x, sc3, sh3, Wsc, W3, out);
    }

    (void)in_sizes; (void)n_in; (void)out_size;
}